// Round 1
// baseline (38677.390 us; speedup 1.0000x reference)
//
#include <hip/hip_runtime.h>
#include <hip/hip_bf16.h>
#include <hip/hip_cooperative_groups.h>

#define NV 128
#define NE 256
#define HD 1024
#define NB 32
#define NS 1024

typedef unsigned short u16;
typedef unsigned short ushort8 __attribute__((ext_vector_type(8)));

__device__ __forceinline__ float bf2f(u16 u){
  unsigned int x = ((unsigned int)u) << 16;
  return __builtin_bit_cast(float, x);
}
__device__ __forceinline__ u16 f2bf(float f){
  unsigned int u = __builtin_bit_cast(unsigned int, f);
  unsigned int r = u + 0x7fffu + ((u >> 16) & 1u);
  return (u16)(r >> 16);
}

// ---------------- K1: XW[v,h] = sum_e emb[v,e]*Wx[h,e] + Wx_b[h] ----------------
__global__ __launch_bounds__(256) void k_xw(const float* __restrict__ emb,
    const float* __restrict__ wxw, const float* __restrict__ wxb,
    float* __restrict__ XW)
{
  __shared__ float es[NE];
  const int v = blockIdx.x;
  for (int i = threadIdx.x; i < NE; i += 256) es[i] = emb[v*NE + i];
  __syncthreads();
  for (int h = threadIdx.x; h < HD; h += 256){
    const float* wr = wxw + (size_t)h * NE;
    float acc = 0.f;
#pragma unroll 4
    for (int e = 0; e < NE; e += 4){
      float4 w4 = *reinterpret_cast<const float4*>(wr + e);
      acc += w4.x*es[e] + w4.y*es[e+1] + w4.z*es[e+2] + w4.w*es[e+3];
    }
    XW[(size_t)v*HD + h] = acc + wxb[h];
  }
}

// ---------------- K2: RNN scan (cooperative, Wh in registers) ----------------
// 128 WGs x 256 thr. WG g owns output rows j in [8g, 8g+8).
// Thread (jr = tid>>5, kc = tid&31) holds Wh[8g+jr][i4*128 + kc*4 + j] , i4<8, j<4.
__global__ __launch_bounds__(256, 1) void k_scan(const int* __restrict__ x,
    const float* __restrict__ whw, const float* __restrict__ whb,
    const float* __restrict__ XW, float* __restrict__ hstate,
    u16* __restrict__ Harc)
{
  namespace cg = cooperative_groups;
  cg::grid_group grid = cg::this_grid();
  __shared__ __align__(16) float hq[8][HD];     // 32 KB: 8 batch rows of h_prev
  __shared__ float part[8][256];                // 8 KB partials
  const int tid = threadIdx.x;
  const int g = blockIdx.x;
  const int kc = tid & 31;
  const int row = g*8 + (tid >> 5);

  float wreg[32];
#pragma unroll
  for (int i4 = 0; i4 < 8; ++i4){
    float4 w4 = *reinterpret_cast<const float4*>(whw + (size_t)row*HD + i4*128 + kc*4);
    wreg[i4*4+0] = w4.x; wreg[i4*4+1] = w4.y; wreg[i4*4+2] = w4.z; wreg[i4*4+3] = w4.w;
  }

  for (int t = 0; t < NS; ++t){
    const float* hprev = hstate + (size_t)((t & 1) ^ 1) * NB * HD;
    float* hcur = hstate + (size_t)(t & 1) * NB * HD;
    for (int q = 0; q < 4; ++q){          // 8 batch rows per quarter
      float4* dst = reinterpret_cast<float4*>(&hq[0][0]);
      if (t == 0){
#pragma unroll
        for (int j = 0; j < 8; ++j) dst[tid + 256*j] = float4{0.f,0.f,0.f,0.f};
      } else {
        const float4* src = reinterpret_cast<const float4*>(hprev + (size_t)q*8*HD);
#pragma unroll
        for (int j = 0; j < 8; ++j) dst[tid + 256*j] = src[tid + 256*j];
      }
      __syncthreads();
#pragma unroll
      for (int b = 0; b < 8; ++b){
        float p = 0.f;
#pragma unroll
        for (int i4 = 0; i4 < 8; ++i4){
          float4 hv = *reinterpret_cast<const float4*>(&hq[b][i4*128 + kc*4]);
          p += wreg[i4*4+0]*hv.x;
          p += wreg[i4*4+1]*hv.y;
          p += wreg[i4*4+2]*hv.z;
          p += wreg[i4*4+3]*hv.w;
        }
        part[b][tid] = p;
      }
      __syncthreads();
      if (tid < 64){
        const int b = tid >> 3, j2 = tid & 7;
        float s = 0.f;
#pragma unroll
        for (int kk = 0; kk < 32; ++kk) s += part[b][j2*32 + kk];
        const int bb = q*8 + b;
        const int r2 = g*8 + j2;
        const int xv = x[bb*NS + t];
        const float val = tanhf(XW[(size_t)xv*HD + r2] + whb[r2] + s);
        hcur[(size_t)bb*HD + r2] = val;
        Harc[((size_t)bb*NS + t)*HD + r2] = f2bf(val);
      }
      // no trailing barrier needed: next load's barrier orders part reuse
    }
    grid.sync();
  }
}

// ---------------- K3: A[r,n] = sum_k H[r,k]*Wa[n,k] + Wa_b[n] ----------------
__global__ __launch_bounds__(256) void k_gemm_A(const u16* __restrict__ Harc,
    const float* __restrict__ waw, const float* __restrict__ wab,
    u16* __restrict__ Aarc)
{
  __shared__ float ht[64][33];
  __shared__ float wt[64][33];
  const int mq = threadIdx.x >> 4;   // 0..15 (4 rows each)
  const int nq = threadIdx.x & 15;   // 0..15 (8... 4 cols each, stride 16)
  const int m0 = blockIdx.x * 64;
  const int n0 = blockIdx.y * 64;
  float acc[4][4] = {};
  const int r = threadIdx.x >> 2;
  const int ko = (threadIdx.x & 3) * 8;
  for (int k0 = 0; k0 < HD; k0 += 32){
    {
      ushort8 hv = *reinterpret_cast<const ushort8*>(Harc + ((size_t)(m0 + r))*HD + k0 + ko);
#pragma unroll
      for (int j = 0; j < 8; ++j) ht[r][ko + j] = bf2f(hv[j]);
      float4 wa = *reinterpret_cast<const float4*>(waw + (size_t)(n0 + r)*HD + k0 + ko);
      float4 wb = *reinterpret_cast<const float4*>(waw + (size_t)(n0 + r)*HD + k0 + ko + 4);
      wt[r][ko+0]=wa.x; wt[r][ko+1]=wa.y; wt[r][ko+2]=wa.z; wt[r][ko+3]=wa.w;
      wt[r][ko+4]=wb.x; wt[r][ko+5]=wb.y; wt[r][ko+6]=wb.z; wt[r][ko+7]=wb.w;
    }
    __syncthreads();
#pragma unroll 4
    for (int kk = 0; kk < 32; ++kk){
      const float a0 = ht[mq*4+0][kk], a1 = ht[mq*4+1][kk],
                  a2 = ht[mq*4+2][kk], a3 = ht[mq*4+3][kk];
#pragma unroll
      for (int j = 0; j < 4; ++j){
        const float bv = wt[nq + 16*j][kk];
        acc[0][j] += a0*bv; acc[1][j] += a1*bv;
        acc[2][j] += a2*bv; acc[3][j] += a3*bv;
      }
    }
    __syncthreads();
  }
#pragma unroll
  for (int i = 0; i < 4; ++i){
#pragma unroll
    for (int j = 0; j < 4; ++j){
      const int m = m0 + mq*4 + i;
      const int n = n0 + nq + 16*j;
      Aarc[(size_t)m*HD + n] = f2bf(acc[i][j] + wab[n]);
    }
  }
}

// ---------------- K4: causal attention, flash-style ----------------
// Q = H (query index t), K = A (key index s<=t), V = H. Per WG: b, 16 queries.
__global__ __launch_bounds__(256) void k_attn(const u16* __restrict__ Harc,
    const u16* __restrict__ Aarc, u16* __restrict__ Ctx)
{
  __shared__ __align__(16) u16 hqs[16][1032];
  __shared__ float sc[64][16];
  __shared__ float mle[16], lle[16], cor[16];
  const int qt = blockIdx.x;
  const int bb = blockIdx.y;
  const int t0 = qt * 16;
  const int q  = threadIdx.x >> 4;   // query within tile
  const int hc = threadIdx.x & 15;   // h-slice selector (64 elems)
  const u16* Hbase = Harc + ((size_t)bb * NS) * HD;

#pragma unroll
  for (int j = 0; j < 8; ++j){
    ushort8 v = *reinterpret_cast<const ushort8*>(Hbase + (size_t)(t0+q)*HD + hc*64 + j*8);
    *reinterpret_cast<ushort8*>(&hqs[q][hc*64 + j*8]) = v;
  }
  if (threadIdx.x < 16){ mle[threadIdx.x] = -1e30f; lle[threadIdx.x] = 0.f; }
  float ctx[64];
#pragma unroll
  for (int e = 0; e < 64; ++e) ctx[e] = 0.f;
  __syncthreads();

  const int smax = t0 + 15;
  for (int s0 = 0; s0 <= smax; s0 += 64){
    // scores: thread computes score(s = s0+hc+16i, query q)
#pragma unroll
    for (int i = 0; i < 4; ++i){
      const int s = s0 + hc + 16*i;
      float acc = -1e30f;
      if (s <= t0 + q){
        acc = 0.f;
        const u16* arow = Aarc + ((size_t)bb*NS + s)*HD;
        for (int k = 0; k < HD; k += 8){
          ushort8 av = *reinterpret_cast<const ushort8*>(arow + k);
          ushort8 hv = *reinterpret_cast<const ushort8*>(&hqs[q][k]);
#pragma unroll
          for (int j = 0; j < 8; ++j) acc += bf2f(av[j]) * bf2f(hv[j]);
        }
      }
      sc[hc + 16*i][q] = acc;
    }
    __syncthreads();
    if (threadIdx.x < 16){
      const int qq = threadIdx.x;
      const float m = mle[qq];
      float mt = m;
      for (int s = 0; s < 64; ++s) mt = fmaxf(mt, sc[s][qq]);
      const float c = __expf(m - mt);
      float ssum = 0.f;
      for (int s = 0; s < 64; ++s){
        const float w = __expf(sc[s][qq] - mt);
        sc[s][qq] = w;
        ssum += w;
      }
      lle[qq] = lle[qq]*c + ssum;
      mle[qq] = mt;
      cor[qq] = c;
    }
    __syncthreads();
    {
      const float c = cor[q];
#pragma unroll
      for (int e = 0; e < 64; ++e) ctx[e] *= c;
      const int slim = min(64, smax + 1 - s0);
      for (int s = 0; s < slim; ++s){
        const float w = sc[s][q];
        const u16* hrow = Hbase + (size_t)(s0+s)*HD + hc*64;
#pragma unroll
        for (int j8 = 0; j8 < 8; ++j8){
          ushort8 hv = *reinterpret_cast<const ushort8*>(hrow + j8*8);
#pragma unroll
          for (int j = 0; j < 8; ++j) ctx[j8*8+j] += w * bf2f(hv[j]);
        }
      }
    }
    __syncthreads();
  }
  const float linv = 1.f / lle[q];
  u16* crow = Ctx + ((size_t)bb*NS + t0 + q)*HD + hc*64;
#pragma unroll
  for (int e = 0; e < 64; ++e) crow[e] = f2bf(ctx[e] * linv);
}

// ---------------- K5: out[r,v] = [H|ctx][r,:] . fc_w[v,:] + fc_b[v] ----------------
__global__ __launch_bounds__(256) void k_out(const u16* __restrict__ Harc,
    const u16* __restrict__ Ctx, const float* __restrict__ fcw,
    const float* __restrict__ fcb, float* __restrict__ out)
{
  __shared__ float cb[64][65];
  __shared__ float ft[128][65];
  const int r0 = blockIdx.x * 64;
  const int vq = threadIdx.x & 15;   // consecutive v lanes
  const int rq = threadIdx.x >> 4;   // 0..15, 4 rows each
  float acc[4][8] = {};
  const int rr = threadIdx.x >> 2;
  const int ko = (threadIdx.x & 3) * 16;
  const int vv = threadIdx.x >> 1;
  const int ko2 = (threadIdx.x & 1) * 32;
  for (int k0 = 0; k0 < 2*HD; k0 += 64){
    {
      const u16* src = (k0 < HD) ? (Harc + (size_t)(r0+rr)*HD + k0 + ko)
                                 : (Ctx  + (size_t)(r0+rr)*HD + (k0 - HD) + ko);
      ushort8 v0 = *reinterpret_cast<const ushort8*>(src);
      ushort8 v1 = *reinterpret_cast<const ushort8*>(src + 8);
#pragma unroll
      for (int j = 0; j < 8; ++j){ cb[rr][ko+j] = bf2f(v0[j]); cb[rr][ko+8+j] = bf2f(v1[j]); }
      const float* fsrc = fcw + (size_t)vv*(2*HD) + k0 + ko2;
#pragma unroll
      for (int j4 = 0; j4 < 8; ++j4){
        float4 f4 = *reinterpret_cast<const float4*>(fsrc + j4*4);
        ft[vv][ko2+j4*4+0]=f4.x; ft[vv][ko2+j4*4+1]=f4.y;
        ft[vv][ko2+j4*4+2]=f4.z; ft[vv][ko2+j4*4+3]=f4.w;
      }
    }
    __syncthreads();
#pragma unroll 4
    for (int kk = 0; kk < 64; ++kk){
      const float a0 = cb[rq*4+0][kk], a1 = cb[rq*4+1][kk],
                  a2 = cb[rq*4+2][kk], a3 = cb[rq*4+3][kk];
#pragma unroll
      for (int j = 0; j < 8; ++j){
        const float bv = ft[vq + 16*j][kk];
        acc[0][j] += a0*bv; acc[1][j] += a1*bv;
        acc[2][j] += a2*bv; acc[3][j] += a3*bv;
      }
    }
    __syncthreads();
  }
#pragma unroll
  for (int i = 0; i < 4; ++i){
#pragma unroll
    for (int j = 0; j < 8; ++j){
      const int r = r0 + rq*4 + i;
      const int v = vq + 16*j;
      out[(size_t)r*NV + v] = acc[i][j] + fcb[v];
    }
  }
}

extern "C" void kernel_launch(void* const* d_in, const int* in_sizes, int n_in,
                              void* d_out, int out_size, void* d_ws, size_t ws_size,
                              hipStream_t stream)
{
  const int*   x   = (const int*)  d_in[0];
  const float* emb = (const float*)d_in[1];
  const float* wxw = (const float*)d_in[2];
  const float* wxb = (const float*)d_in[3];
  const float* whw = (const float*)d_in[4];
  const float* whb = (const float*)d_in[5];
  const float* waw = (const float*)d_in[6];
  const float* wab = (const float*)d_in[7];
  const float* fcw = (const float*)d_in[8];
  const float* fcb = (const float*)d_in[9];
  float* out = (float*)d_out;

  char* ws = (char*)d_ws;
  float* XW     = (float*)(ws);                       // 128*1024*4      = 524288
  float* hstate = (float*)(ws + 524288);              // 2*32*1024*4    = 262144
  u16*   Harc   = (u16*)  (ws + 786432);              // 32*1024*1024*2 = 67108864
  u16*   Aarc   = (u16*)  (ws + 67895296);            // 67108864
  u16*   Ctx    = (u16*)  (ws + 135004160);           // 67108864 -> total ~202.1 MB

  k_xw<<<dim3(NV), dim3(256), 0, stream>>>(emb, wxw, wxb, XW);

  {
    void* args[] = { (void*)&x, (void*)&whw, (void*)&whb, (void*)&XW,
                     (void*)&hstate, (void*)&Harc };
    hipLaunchCooperativeKernel((const void*)k_scan, dim3(128), dim3(256),
                               args, 0, stream);
  }

  k_gemm_A<<<dim3(512, 16), dim3(256), 0, stream>>>(Harc, waw, wab, Aarc);
  k_attn<<<dim3(64, 32), dim3(256), 0, stream>>>(Harc, Aarc, Ctx);
  k_out<<<dim3(512), dim3(256), 0, stream>>>(Harc, Ctx, fcw, fcb, out);
}

// Round 2
// 25001.373 us; speedup vs baseline: 1.5470x; 1.5470x over previous
//
#include <hip/hip_runtime.h>
#include <hip/hip_bf16.h>
#include <hip/hip_cooperative_groups.h>

#define NV 128
#define NE 256
#define HD 1024
#define NB 32
#define NS 1024

typedef unsigned short u16;
typedef unsigned short ushort8 __attribute__((ext_vector_type(8)));

__device__ __forceinline__ float bf2f(u16 u){
  unsigned int x = ((unsigned int)u) << 16;
  return __builtin_bit_cast(float, x);
}
__device__ __forceinline__ u16 f2bf(float f){
  unsigned int u = __builtin_bit_cast(unsigned int, f);
  unsigned int r = u + 0x7fffu + ((u >> 16) & 1u);
  return (u16)(r >> 16);
}

// ---------------- K1: XW[v,h] = sum_e emb[v,e]*Wx[h,e] + Wx_b[h] ----------------
__global__ __launch_bounds__(256) void k_xw(const float* __restrict__ emb,
    const float* __restrict__ wxw, const float* __restrict__ wxb,
    float* __restrict__ XW)
{
  __shared__ float es[NE];
  const int v = blockIdx.x;
  for (int i = threadIdx.x; i < NE; i += 256) es[i] = emb[v*NE + i];
  __syncthreads();
  for (int h = threadIdx.x; h < HD; h += 256){
    const float* wr = wxw + (size_t)h * NE;
    float acc = 0.f;
#pragma unroll 4
    for (int e = 0; e < NE; e += 4){
      float4 w4 = *reinterpret_cast<const float4*>(wr + e);
      acc += w4.x*es[e] + w4.y*es[e+1] + w4.z*es[e+2] + w4.w*es[e+3];
    }
    XW[(size_t)v*HD + h] = acc + wxb[h];
  }
}

// ---------------- K2: RNN scan, per-batch-group barriers ----------------
// 256 WGs x 256 thr. Group g = bid&7 (8 groups; each maps to one XCD under the
// usual round-robin dispatch — perf heuristic only). Group owns batches 4g..4g+3.
// Member m = bid>>3 owns rows [m*32, m*32+32). Thread: row = m*32 + (tid>>3),
// k-chunk c = tid&7 covering k in [c*128, c*128+128), loaded ROTATED by
// (4*(j+c))&127 so LDS reads are bank-conflict-free.
__global__ __launch_bounds__(256, 1) void k_scan2(const int* __restrict__ x,
    const float* __restrict__ whw, const float* __restrict__ whb,
    const float* __restrict__ XW, float* __restrict__ hstate,
    u16* __restrict__ Harc, unsigned int* __restrict__ cnt)
{
  __shared__ __align__(16) float hs[4096];   // 4 batches x 1024
  __shared__ int xs[4096];                   // 4 batches x 1024 token ids
  const int tid = threadIdx.x;
  const int g = blockIdx.x & 7;
  const int m = blockIdx.x >> 3;
  const int c = tid & 7;
  const int rp = tid >> 3;
  const int row = m*32 + rp;

  for (int i = tid; i < 4096; i += 256) xs[i] = x[g*4096 + i];

  float4 wv[32];
#pragma unroll
  for (int j = 0; j < 32; ++j){
    const int k = (4*(j + c)) & 127;
    wv[j] = *reinterpret_cast<const float4*>(whw + (size_t)row*HD + c*128 + k);
  }
  const float bias = whb[row];
  unsigned int* bar = cnt + g*32;            // 128B-padded per-group counter
  __syncthreads();                           // xs ready

  for (int t = 0; t < NS; ++t){
    const float* hin  = hstate + (size_t)(t & 1)*(NB*HD) + g*4*HD;
    float*       hout = hstate + (size_t)((t & 1)^1)*(NB*HD) + g*4*HD;
    // stage 4 batch rows of h (16 KB), coalesced + conflict-free
#pragma unroll
    for (int q = 0; q < 4; ++q)
      *reinterpret_cast<float4*>(&hs[q*1024 + tid*4]) =
        *reinterpret_cast<const float4*>(hin + q*1024 + tid*4);
    // prefetch the per-step gather operands early (hide L2 latency under FMAs)
    int xv = 0; float xwv = 0.f;
    if (c < 4){
      xv  = xs[c*1024 + t];
      xwv = XW[(size_t)xv*HD + row];
    }
    __syncthreads();
    float s0=0.f, s1=0.f, s2=0.f, s3=0.f;
#pragma unroll
    for (int j = 0; j < 32; ++j){
      const int k = c*128 + ((4*(j + c)) & 127);
      float4 h0 = *reinterpret_cast<const float4*>(&hs[k]);
      float4 h1 = *reinterpret_cast<const float4*>(&hs[1024 + k]);
      float4 h2 = *reinterpret_cast<const float4*>(&hs[2048 + k]);
      float4 h3 = *reinterpret_cast<const float4*>(&hs[3072 + k]);
      s0 += wv[j].x*h0.x + wv[j].y*h0.y + wv[j].z*h0.z + wv[j].w*h0.w;
      s1 += wv[j].x*h1.x + wv[j].y*h1.y + wv[j].z*h1.z + wv[j].w*h1.w;
      s2 += wv[j].x*h2.x + wv[j].y*h2.y + wv[j].z*h2.z + wv[j].w*h2.w;
      s3 += wv[j].x*h3.x + wv[j].y*h3.y + wv[j].z*h3.z + wv[j].w*h3.w;
    }
    // butterfly reduce across the 8 chunk-lanes (same octet, same wave)
#pragma unroll
    for (int mm = 1; mm <= 4; mm <<= 1){
      s0 += __shfl_xor(s0, mm);
      s1 += __shfl_xor(s1, mm);
      s2 += __shfl_xor(s2, mm);
      s3 += __shfl_xor(s3, mm);
    }
    if (c < 4){
      const float sv = (c==0) ? s0 : (c==1) ? s1 : (c==2) ? s2 : s3;
      const float val = tanhf(xwv + bias + sv);
      hout[c*HD + row] = val;
      Harc[(((size_t)(g*4 + c))*NS + t)*HD + row] = f2bf(val);
    }
    __syncthreads();   // drains each wave's vmem stores (vmcnt(0) before s_barrier)
    if (tid == 0){
      __hip_atomic_fetch_add(bar, 1u, __ATOMIC_RELEASE, __HIP_MEMORY_SCOPE_AGENT);
      const unsigned int target = 32u*(unsigned)(t+1);
      while (__hip_atomic_load(bar, __ATOMIC_ACQUIRE, __HIP_MEMORY_SCOPE_AGENT) < target)
        __builtin_amdgcn_s_sleep(1);
    }
    __syncthreads();
  }
}

// ---------------- K3: A[r,n] = sum_k H[r,k]*Wa[n,k] + Wa_b[n] ----------------
__global__ __launch_bounds__(256) void k_gemm_A(const u16* __restrict__ Harc,
    const float* __restrict__ waw, const float* __restrict__ wab,
    u16* __restrict__ Aarc)
{
  __shared__ float ht[64][33];
  __shared__ float wt[64][33];
  const int mq = threadIdx.x >> 4;
  const int nq = threadIdx.x & 15;
  const int m0 = blockIdx.x * 64;
  const int n0 = blockIdx.y * 64;
  float acc[4][4] = {};
  const int r = threadIdx.x >> 2;
  const int ko = (threadIdx.x & 3) * 8;
  for (int k0 = 0; k0 < HD; k0 += 32){
    {
      ushort8 hv = *reinterpret_cast<const ushort8*>(Harc + ((size_t)(m0 + r))*HD + k0 + ko);
#pragma unroll
      for (int j = 0; j < 8; ++j) ht[r][ko + j] = bf2f(hv[j]);
      float4 wa = *reinterpret_cast<const float4*>(waw + (size_t)(n0 + r)*HD + k0 + ko);
      float4 wb = *reinterpret_cast<const float4*>(waw + (size_t)(n0 + r)*HD + k0 + ko + 4);
      wt[r][ko+0]=wa.x; wt[r][ko+1]=wa.y; wt[r][ko+2]=wa.z; wt[r][ko+3]=wa.w;
      wt[r][ko+4]=wb.x; wt[r][ko+5]=wb.y; wt[r][ko+6]=wb.z; wt[r][ko+7]=wb.w;
    }
    __syncthreads();
#pragma unroll 4
    for (int kk = 0; kk < 32; ++kk){
      const float a0 = ht[mq*4+0][kk], a1 = ht[mq*4+1][kk],
                  a2 = ht[mq*4+2][kk], a3 = ht[mq*4+3][kk];
#pragma unroll
      for (int j = 0; j < 4; ++j){
        const float bv = wt[nq + 16*j][kk];
        acc[0][j] += a0*bv; acc[1][j] += a1*bv;
        acc[2][j] += a2*bv; acc[3][j] += a3*bv;
      }
    }
    __syncthreads();
  }
#pragma unroll
  for (int i = 0; i < 4; ++i){
#pragma unroll
    for (int j = 0; j < 4; ++j){
      const int mI = m0 + mq*4 + i;
      const int n = n0 + nq + 16*j;
      Aarc[(size_t)mI*HD + n] = f2bf(acc[i][j] + wab[n]);
    }
  }
}

// ---------------- K4: causal attention, flash-style ----------------
__global__ __launch_bounds__(256) void k_attn(const u16* __restrict__ Harc,
    const u16* __restrict__ Aarc, u16* __restrict__ Ctx)
{
  __shared__ __align__(16) u16 hqs[16][1032];
  __shared__ float sc[64][16];
  __shared__ float mle[16], lle[16], cor[16];
  const int qt = blockIdx.x;
  const int bb = blockIdx.y;
  const int t0 = qt * 16;
  const int q  = threadIdx.x >> 4;
  const int hc = threadIdx.x & 15;
  const u16* Hbase = Harc + ((size_t)bb * NS) * HD;

#pragma unroll
  for (int j = 0; j < 8; ++j){
    ushort8 v = *reinterpret_cast<const ushort8*>(Hbase + (size_t)(t0+q)*HD + hc*64 + j*8);
    *reinterpret_cast<ushort8*>(&hqs[q][hc*64 + j*8]) = v;
  }
  if (threadIdx.x < 16){ mle[threadIdx.x] = -1e30f; lle[threadIdx.x] = 0.f; }
  float ctx[64];
#pragma unroll
  for (int e = 0; e < 64; ++e) ctx[e] = 0.f;
  __syncthreads();

  const int smax = t0 + 15;
  for (int s0 = 0; s0 <= smax; s0 += 64){
#pragma unroll
    for (int i = 0; i < 4; ++i){
      const int s = s0 + hc + 16*i;
      float acc = -1e30f;
      if (s <= t0 + q){
        acc = 0.f;
        const u16* arow = Aarc + ((size_t)bb*NS + s)*HD;
        for (int k = 0; k < HD; k += 8){
          ushort8 av = *reinterpret_cast<const ushort8*>(arow + k);
          ushort8 hv = *reinterpret_cast<const ushort8*>(&hqs[q][k]);
#pragma unroll
          for (int j = 0; j < 8; ++j) acc += bf2f(av[j]) * bf2f(hv[j]);
        }
      }
      sc[hc + 16*i][q] = acc;
    }
    __syncthreads();
    if (threadIdx.x < 16){
      const int qq = threadIdx.x;
      const float mOld = mle[qq];
      float mt = mOld;
      for (int s = 0; s < 64; ++s) mt = fmaxf(mt, sc[s][qq]);
      const float cc = __expf(mOld - mt);
      float ssum = 0.f;
      for (int s = 0; s < 64; ++s){
        const float w = __expf(sc[s][qq] - mt);
        sc[s][qq] = w;
        ssum += w;
      }
      lle[qq] = lle[qq]*cc + ssum;
      mle[qq] = mt;
      cor[qq] = cc;
    }
    __syncthreads();
    {
      const float cc = cor[q];
#pragma unroll
      for (int e = 0; e < 64; ++e) ctx[e] *= cc;
      const int slim = min(64, smax + 1 - s0);
      for (int s = 0; s < slim; ++s){
        const float w = sc[s][q];
        const u16* hrow = Hbase + (size_t)(s0+s)*HD + hc*64;
#pragma unroll
        for (int j8 = 0; j8 < 8; ++j8){
          ushort8 hv = *reinterpret_cast<const ushort8*>(hrow + j8*8);
#pragma unroll
          for (int j = 0; j < 8; ++j) ctx[j8*8+j] += w * bf2f(hv[j]);
        }
      }
    }
    __syncthreads();
  }
  const float linv = 1.f / lle[q];
  u16* crow = Ctx + ((size_t)bb*NS + t0 + q)*HD + hc*64;
#pragma unroll
  for (int e = 0; e < 64; ++e) crow[e] = f2bf(ctx[e] * linv);
}

// ---------------- K5: out[r,v] = [H|ctx][r,:] . fc_w[v,:] + fc_b[v] ----------------
__global__ __launch_bounds__(256) void k_out(const u16* __restrict__ Harc,
    const u16* __restrict__ Ctx, const float* __restrict__ fcw,
    const float* __restrict__ fcb, float* __restrict__ out)
{
  __shared__ float cb[64][65];
  __shared__ float ft[128][65];
  const int r0 = blockIdx.x * 64;
  const int vq = threadIdx.x & 15;
  const int rq = threadIdx.x >> 4;
  float acc[4][8] = {};
  const int rr = threadIdx.x >> 2;
  const int ko = (threadIdx.x & 3) * 16;
  const int vv = threadIdx.x >> 1;
  const int ko2 = (threadIdx.x & 1) * 32;
  for (int k0 = 0; k0 < 2*HD; k0 += 64){
    {
      const u16* src = (k0 < HD) ? (Harc + (size_t)(r0+rr)*HD + k0 + ko)
                                 : (Ctx  + (size_t)(r0+rr)*HD + (k0 - HD) + ko);
      ushort8 v0 = *reinterpret_cast<const ushort8*>(src);
      ushort8 v1 = *reinterpret_cast<const ushort8*>(src + 8);
#pragma unroll
      for (int j = 0; j < 8; ++j){ cb[rr][ko+j] = bf2f(v0[j]); cb[rr][ko+8+j] = bf2f(v1[j]); }
      const float* fsrc = fcw + (size_t)vv*(2*HD) + k0 + ko2;
#pragma unroll
      for (int j4 = 0; j4 < 8; ++j4){
        float4 f4 = *reinterpret_cast<const float4*>(fsrc + j4*4);
        ft[vv][ko2+j4*4+0]=f4.x; ft[vv][ko2+j4*4+1]=f4.y;
        ft[vv][ko2+j4*4+2]=f4.z; ft[vv][ko2+j4*4+3]=f4.w;
      }
    }
    __syncthreads();
#pragma unroll 4
    for (int kk = 0; kk < 64; ++kk){
      const float a0 = cb[rq*4+0][kk], a1 = cb[rq*4+1][kk],
                  a2 = cb[rq*4+2][kk], a3 = cb[rq*4+3][kk];
#pragma unroll
      for (int j = 0; j < 8; ++j){
        const float bv = ft[vq + 16*j][kk];
        acc[0][j] += a0*bv; acc[1][j] += a1*bv;
        acc[2][j] += a2*bv; acc[3][j] += a3*bv;
      }
    }
    __syncthreads();
  }
#pragma unroll
  for (int i = 0; i < 4; ++i){
#pragma unroll
    for (int j = 0; j < 8; ++j){
      const int r = r0 + rq*4 + i;
      const int v = vq + 16*j;
      out[(size_t)r*NV + v] = acc[i][j] + fcb[v];
    }
  }
}

extern "C" void kernel_launch(void* const* d_in, const int* in_sizes, int n_in,
                              void* d_out, int out_size, void* d_ws, size_t ws_size,
                              hipStream_t stream)
{
  const int*   x   = (const int*)  d_in[0];
  const float* emb = (const float*)d_in[1];
  const float* wxw = (const float*)d_in[2];
  const float* wxb = (const float*)d_in[3];
  const float* whw = (const float*)d_in[4];
  const float* whb = (const float*)d_in[5];
  const float* waw = (const float*)d_in[6];
  const float* wab = (const float*)d_in[7];
  const float* fcw = (const float*)d_in[8];
  const float* fcb = (const float*)d_in[9];
  float* out = (float*)d_out;

  char* ws = (char*)d_ws;
  unsigned int* cnt = (unsigned int*)(ws);            // 8 groups * 128B pad (4 KB reserved)
  float* hstate = (float*)(ws + 4096);                // 2*32*1024*4 = 262144
  float* XW     = (float*)(ws + 266240);              // 128*1024*4  = 524288
  u16*   Harc   = (u16*)  (ws + 790528);              // 32*1024*1024*2 = 67108864
  u16*   Aarc   = (u16*)  (ws + 67899392);            // 67108864
  u16*   Ctx    = (u16*)  (ws + 135008256);           // 67108864 -> total ~202.1 MB

  // zero the barrier counters + both hstate ping-pong buffers (h0 = 0)
  hipMemsetAsync(ws, 0, 266240, stream);

  k_xw<<<dim3(NV), dim3(256), 0, stream>>>(emb, wxw, wxb, XW);

  {
    void* args[] = { (void*)&x, (void*)&whw, (void*)&whb, (void*)&XW,
                     (void*)&hstate, (void*)&Harc, (void*)&cnt };
    hipLaunchCooperativeKernel((const void*)k_scan2, dim3(256), dim3(256),
                               args, 0, stream);
  }

  k_gemm_A<<<dim3(512, 16), dim3(256), 0, stream>>>(Harc, waw, wab, Aarc);
  k_attn<<<dim3(64, 32), dim3(256), 0, stream>>>(Harc, Aarc, Ctx);
  k_out<<<dim3(512), dim3(256), 0, stream>>>(Harc, Ctx, fcw, fcb, out);
}

// Round 4
// 11986.566 us; speedup vs baseline: 3.2267x; 2.0858x over previous
//
#include <hip/hip_runtime.h>
#include <hip/hip_bf16.h>
#include <hip/hip_cooperative_groups.h>

#define NV 128
#define NE 256
#define HD 1024
#define NB 32
#define NS 1024

typedef unsigned short u16;
typedef unsigned short ushort8 __attribute__((ext_vector_type(8)));
typedef unsigned short u16x4 __attribute__((ext_vector_type(4)));
typedef short bf16x8 __attribute__((ext_vector_type(8)));
typedef float f32x4 __attribute__((ext_vector_type(4)));

#define MFMA16(a, b, c) __builtin_amdgcn_mfma_f32_16x16x32_bf16(a, b, c, 0, 0, 0)

__device__ __forceinline__ float bf2f(u16 u){
  unsigned int x = ((unsigned int)u) << 16;
  return __builtin_bit_cast(float, x);
}
__device__ __forceinline__ u16 f2bf(float f){
  unsigned int u = __builtin_bit_cast(unsigned int, f);
  unsigned int r = u + 0x7fffu + ((u >> 16) & 1u);
  return (u16)(r >> 16);
}

// ---------------- K0: fp32 weights -> bf16 copies ----------------
__global__ __launch_bounds__(256) void k_cvt(const float* __restrict__ waw,
    const float* __restrict__ fcw, u16* __restrict__ wa_bf, u16* __restrict__ fc_bf)
{
  const int i = blockIdx.x * 256 + threadIdx.x;
  if (i < 1048576) wa_bf[i] = f2bf(waw[i]);
  const int j = i - 1048576;
  if (j >= 0 && j < 262144) fc_bf[j] = f2bf(fcw[j]);
}

// ---------------- K1: XW[v,h] = sum_e emb[v,e]*Wx[h,e] + Wx_b[h] ----------------
__global__ __launch_bounds__(256) void k_xw(const float* __restrict__ emb,
    const float* __restrict__ wxw, const float* __restrict__ wxb,
    float* __restrict__ XW)
{
  __shared__ float es[NE];
  const int v = blockIdx.x;
  for (int i = threadIdx.x; i < NE; i += 256) es[i] = emb[v*NE + i];
  __syncthreads();
  for (int h = threadIdx.x; h < HD; h += 256){
    const float* wr = wxw + (size_t)h * NE;
    float acc = 0.f;
#pragma unroll 4
    for (int e = 0; e < NE; e += 4){
      float4 w4 = *reinterpret_cast<const float4*>(wr + e);
      acc += w4.x*es[e] + w4.y*es[e+1] + w4.z*es[e+2] + w4.w*es[e+3];
    }
    XW[(size_t)v*HD + h] = acc + wxb[h];
  }
}

// ---------------- K2: RNN scan, per-batch-group barriers (unchanged) ----------------
__global__ __launch_bounds__(256, 1) void k_scan2(const int* __restrict__ x,
    const float* __restrict__ whw, const float* __restrict__ whb,
    const float* __restrict__ XW, float* __restrict__ hstate,
    u16* __restrict__ Harc, unsigned int* __restrict__ cnt)
{
  __shared__ __align__(16) float hs[4096];
  __shared__ int xs[4096];
  const int tid = threadIdx.x;
  const int g = blockIdx.x & 7;
  const int m = blockIdx.x >> 3;
  const int c = tid & 7;
  const int rp = tid >> 3;
  const int row = m*32 + rp;

  for (int i = tid; i < 4096; i += 256) xs[i] = x[g*4096 + i];

  float4 wv[32];
#pragma unroll
  for (int j = 0; j < 32; ++j){
    const int k = (4*(j + c)) & 127;
    wv[j] = *reinterpret_cast<const float4*>(whw + (size_t)row*HD + c*128 + k);
  }
  const float bias = whb[row];
  unsigned int* bar = cnt + g*32;
  __syncthreads();

  for (int t = 0; t < NS; ++t){
    const float* hin  = hstate + (size_t)(t & 1)*(NB*HD) + g*4*HD;
    float*       hout = hstate + (size_t)((t & 1)^1)*(NB*HD) + g*4*HD;
#pragma unroll
    for (int q = 0; q < 4; ++q)
      *reinterpret_cast<float4*>(&hs[q*1024 + tid*4]) =
        *reinterpret_cast<const float4*>(hin + q*1024 + tid*4);
    int xv = 0; float xwv = 0.f;
    if (c < 4){
      xv  = xs[c*1024 + t];
      xwv = XW[(size_t)xv*HD + row];
    }
    __syncthreads();
    float s0=0.f, s1=0.f, s2=0.f, s3=0.f;
#pragma unroll
    for (int j = 0; j < 32; ++j){
      const int k = c*128 + ((4*(j + c)) & 127);
      float4 h0 = *reinterpret_cast<const float4*>(&hs[k]);
      float4 h1 = *reinterpret_cast<const float4*>(&hs[1024 + k]);
      float4 h2 = *reinterpret_cast<const float4*>(&hs[2048 + k]);
      float4 h3 = *reinterpret_cast<const float4*>(&hs[3072 + k]);
      s0 += wv[j].x*h0.x + wv[j].y*h0.y + wv[j].z*h0.z + wv[j].w*h0.w;
      s1 += wv[j].x*h1.x + wv[j].y*h1.y + wv[j].z*h1.z + wv[j].w*h1.w;
      s2 += wv[j].x*h2.x + wv[j].y*h2.y + wv[j].z*h2.z + wv[j].w*h2.w;
      s3 += wv[j].x*h3.x + wv[j].y*h3.y + wv[j].z*h3.z + wv[j].w*h3.w;
    }
#pragma unroll
    for (int mm = 1; mm <= 4; mm <<= 1){
      s0 += __shfl_xor(s0, mm);
      s1 += __shfl_xor(s1, mm);
      s2 += __shfl_xor(s2, mm);
      s3 += __shfl_xor(s3, mm);
    }
    if (c < 4){
      const float sv = (c==0) ? s0 : (c==1) ? s1 : (c==2) ? s2 : s3;
      const float val = tanhf(xwv + bias + sv);
      hout[c*HD + row] = val;
      Harc[(((size_t)(g*4 + c))*NS + t)*HD + row] = f2bf(val);
    }
    __syncthreads();
    if (tid == 0){
      __hip_atomic_fetch_add(bar, 1u, __ATOMIC_RELEASE, __HIP_MEMORY_SCOPE_AGENT);
      const unsigned int target = 32u*(unsigned)(t+1);
      while (__hip_atomic_load(bar, __ATOMIC_ACQUIRE, __HIP_MEMORY_SCOPE_AGENT) < target)
        __builtin_amdgcn_s_sleep(1);
    }
    __syncthreads();
  }
}

// ---------------- K3: A = H @ Wa^T + b  (MFMA, 128x128 tile) ----------------
__global__ __launch_bounds__(256) void k_gemm_A(const u16* __restrict__ Harc,
    const u16* __restrict__ wa_bf, const float* __restrict__ wab,
    u16* __restrict__ Aarc)
{
  __shared__ u16 As[128][40];
  __shared__ u16 Bs[128][40];
  const int tid = threadIdx.x;
  const int m0 = blockIdx.x * 128;
  const int n0 = blockIdx.y * 128;
  const int l = tid & 63, w = tid >> 6;
  const int wr = w >> 1, wc = w & 1;
  const int lr = l & 15, lg = l >> 4;
  const int srow = tid >> 1, shalf = (tid & 1) * 16;
  f32x4 acc[4][4] = {};
  for (int k0 = 0; k0 < 1024; k0 += 32){
    {
      const u16* a = Harc + (size_t)(m0 + srow)*HD + k0 + shalf;
      ushort8 a0 = *(const ushort8*)a, a1 = *(const ushort8*)(a+8);
      const u16* b = wa_bf + (size_t)(n0 + srow)*HD + k0 + shalf;
      ushort8 b0 = *(const ushort8*)b, b1 = *(const ushort8*)(b+8);
      *(ushort8*)&As[srow][shalf] = a0; *(ushort8*)&As[srow][shalf+8] = a1;
      *(ushort8*)&Bs[srow][shalf] = b0; *(ushort8*)&Bs[srow][shalf+8] = b1;
    }
    __syncthreads();
    bf16x8 af[4], bfr[4];
#pragma unroll
    for (int i = 0; i < 4; ++i){
      af[i]  = *(const bf16x8*)&As[wr*64 + i*16 + lr][lg*8];
      bfr[i] = *(const bf16x8*)&Bs[wc*64 + i*16 + lr][lg*8];
    }
#pragma unroll
    for (int i = 0; i < 4; ++i)
#pragma unroll
      for (int j = 0; j < 4; ++j)
        acc[i][j] = MFMA16(af[i], bfr[j], acc[i][j]);
    __syncthreads();
  }
#pragma unroll
  for (int i = 0; i < 4; ++i){
    const int row = m0 + wr*64 + i*16 + lg*4;
#pragma unroll
    for (int j = 0; j < 4; ++j){
      const int col = n0 + wc*64 + j*16 + lr;
      const float bias = wab[col];
#pragma unroll
      for (int r = 0; r < 4; ++r)
        Aarc[(size_t)(row + r)*HD + col] = f2bf(acc[i][j][r] + bias);
    }
  }
}

// ---------------- K4a: S[b,t,s] = H[b,t]·A[b,s]  (causal tiles only) ----------------
__global__ __launch_bounds__(256) void k_scores(const u16* __restrict__ Harc,
    const u16* __restrict__ Aarc, u16* __restrict__ SW)
{
  if (blockIdx.x > blockIdx.y) return;   // s-tile beyond t-tile: never read
  __shared__ u16 As[128][40];
  __shared__ u16 Bs[128][40];
  const int tid = threadIdx.x;
  const int bz = blockIdx.z;
  const int m0 = blockIdx.y * 128;   // t
  const int n0 = blockIdx.x * 128;   // s
  const u16* Hb = Harc + (size_t)bz * NS * HD;
  const u16* Ab = Aarc + (size_t)bz * NS * HD;
  u16* Sb = SW + ((size_t)bz << 20);
  const int l = tid & 63, w = tid >> 6;
  const int wr = w >> 1, wc = w & 1;
  const int lr = l & 15, lg = l >> 4;
  const int srow = tid >> 1, shalf = (tid & 1) * 16;
  f32x4 acc[4][4] = {};
  for (int k0 = 0; k0 < 1024; k0 += 32){
    {
      const u16* a = Hb + (size_t)(m0 + srow)*HD + k0 + shalf;
      ushort8 a0 = *(const ushort8*)a, a1 = *(const ushort8*)(a+8);
      const u16* b = Ab + (size_t)(n0 + srow)*HD + k0 + shalf;
      ushort8 b0 = *(const ushort8*)b, b1 = *(const ushort8*)(b+8);
      *(ushort8*)&As[srow][shalf] = a0; *(ushort8*)&As[srow][shalf+8] = a1;
      *(ushort8*)&Bs[srow][shalf] = b0; *(ushort8*)&Bs[srow][shalf+8] = b1;
    }
    __syncthreads();
    bf16x8 af[4], bfr[4];
#pragma unroll
    for (int i = 0; i < 4; ++i){
      af[i]  = *(const bf16x8*)&As[wr*64 + i*16 + lr][lg*8];
      bfr[i] = *(const bf16x8*)&Bs[wc*64 + i*16 + lr][lg*8];
    }
#pragma unroll
    for (int i = 0; i < 4; ++i)
#pragma unroll
      for (int j = 0; j < 4; ++j)
        acc[i][j] = MFMA16(af[i], bfr[j], acc[i][j]);
    __syncthreads();
  }
#pragma unroll
  for (int i = 0; i < 4; ++i){
    const int row = m0 + wr*64 + i*16 + lg*4;
#pragma unroll
    for (int j = 0; j < 4; ++j){
      const int col = n0 + wc*64 + j*16 + lr;
#pragma unroll
      for (int r = 0; r < 4; ++r)
        Sb[((size_t)(row + r) << 10) + col] = f2bf(acc[i][j][r]);
    }
  }
}

// ---------------- K4b: row softmax over s (in place, zero-fill s>t) ----------------
__global__ __launch_bounds__(256) void k_softmax(u16* __restrict__ SW)
{
  const int bid = blockIdx.x;
  const int b = bid >> 10, t = bid & 1023;
  u16* row = SW + ((size_t)b << 20) + ((size_t)t << 10);
  const int i0 = threadIdx.x * 4;
  u16x4 v = *(const u16x4*)(row + i0);
  float x[4];
#pragma unroll
  for (int j = 0; j < 4; ++j) x[j] = (i0 + j <= t) ? bf2f(v[j]) : -1e30f;
  float m = fmaxf(fmaxf(x[0], x[1]), fmaxf(x[2], x[3]));
#pragma unroll
  for (int o = 1; o < 64; o <<= 1) m = fmaxf(m, __shfl_xor(m, o));
  __shared__ float redm[4], reds[4];
  if ((threadIdx.x & 63) == 0) redm[threadIdx.x >> 6] = m;
  __syncthreads();
  m = fmaxf(fmaxf(redm[0], redm[1]), fmaxf(redm[2], redm[3]));
  float e[4]; float s = 0.f;
#pragma unroll
  for (int j = 0; j < 4; ++j){ e[j] = __expf(x[j] - m); s += e[j]; }
#pragma unroll
  for (int o = 1; o < 64; o <<= 1) s += __shfl_xor(s, o);
  if ((threadIdx.x & 63) == 0) reds[threadIdx.x >> 6] = s;
  __syncthreads();
  s = reds[0] + reds[1] + reds[2] + reds[3];
  const float inv = 1.f / s;
  u16x4 o4;
#pragma unroll
  for (int j = 0; j < 4; ++j) o4[j] = f2bf(e[j] * inv);
  *(u16x4*)(row + i0) = o4;
}

// ---------------- K4c: Ctx[b,t,e] = sum_s W[b,t,s] * H[b,s,e] ----------------
__global__ __launch_bounds__(256) void k_pv(const u16* __restrict__ SW,
    const u16* __restrict__ Harc, u16* __restrict__ Ctx)
{
  __shared__ u16 As[128][40];   // W rows t, cols s
  __shared__ u16 Bs[128][40];   // H^T rows e, cols s
  const int tid = threadIdx.x;
  const int bz = blockIdx.z;
  const int t0 = blockIdx.x * 128;
  const int e0 = blockIdx.y * 128;
  const u16* Wb = SW + ((size_t)bz << 20);
  const u16* Hb = Harc + (size_t)bz * NS * HD;
  u16* Cb = Ctx + (size_t)bz * NS * HD;
  const int l = tid & 63, w = tid >> 6;
  const int wr = w >> 1, wc = w & 1;
  const int lr = l & 15, lg = l >> 4;
  const int srow = tid >> 1, shalf = (tid & 1) * 16;
  const int sIdx = tid & 31, ec = tid >> 5;
  const int ksteps = (blockIdx.x + 1) * 4;    // s < t0 + 128 (causal bound)
  f32x4 acc[4][4] = {};
  for (int ks = 0; ks < ksteps; ++ks){
    const int k0 = ks * 32;
    {
      const u16* a = Wb + ((size_t)(t0 + srow) << 10) + k0 + shalf;
      ushort8 a0 = *(const ushort8*)a, a1 = *(const ushort8*)(a+8);
      const u16* b = Hb + (size_t)(k0 + sIdx)*HD + e0 + ec*16;
      ushort8 b0 = *(const ushort8*)b, b1 = *(const ushort8*)(b+8);
      *(ushort8*)&As[srow][shalf] = a0; *(ushort8*)&As[srow][shalf+8] = a1;
#pragma unroll
      for (int i = 0; i < 8; ++i){
        Bs[ec*16 + i][sIdx] = b0[i];
        Bs[ec*16 + 8 + i][sIdx] = b1[i];
      }
    }
    __syncthreads();
    bf16x8 af[4], bfr[4];
#pragma unroll
    for (int i = 0; i < 4; ++i){
      af[i]  = *(const bf16x8*)&As[wr*64 + i*16 + lr][lg*8];
      bfr[i] = *(const bf16x8*)&Bs[wc*64 + i*16 + lr][lg*8];
    }
#pragma unroll
    for (int i = 0; i < 4; ++i)
#pragma unroll
      for (int j = 0; j < 4; ++j)
        acc[i][j] = MFMA16(af[i], bfr[j], acc[i][j]);
    __syncthreads();
  }
#pragma unroll
  for (int i = 0; i < 4; ++i){
    const int row = t0 + wr*64 + i*16 + lg*4;
#pragma unroll
    for (int j = 0; j < 4; ++j){
      const int col = e0 + wc*64 + j*16 + lr;
#pragma unroll
      for (int r = 0; r < 4; ++r)
        Cb[(size_t)(row + r)*HD + col] = f2bf(acc[i][j][r]);
    }
  }
}

// ---------------- K5: out = [H|ctx] @ fc^T + b  (MFMA, N=128) ----------------
__global__ __launch_bounds__(256) void k_out2(const u16* __restrict__ Harc,
    const u16* __restrict__ Ctx, const u16* __restrict__ fc_bf,
    const float* __restrict__ fcb, float* __restrict__ out)
{
  __shared__ u16 As[128][40];
  __shared__ u16 Bs[128][40];
  const int tid = threadIdx.x;
  const int m0 = blockIdx.x * 128;
  const int l = tid & 63, w = tid >> 6;
  const int wr = w >> 1, wc = w & 1;
  const int lr = l & 15, lg = l >> 4;
  const int srow = tid >> 1, shalf = (tid & 1) * 16;
  f32x4 acc[4][4] = {};
  for (int k0 = 0; k0 < 2048; k0 += 32){
    {
      const u16* abase = (k0 < 1024) ? Harc : Ctx;
      const u16* a = abase + (size_t)(m0 + srow)*HD + (k0 & 1023) + shalf;
      ushort8 a0 = *(const ushort8*)a, a1 = *(const ushort8*)(a+8);
      const u16* b = fc_bf + (size_t)srow*2048 + k0 + shalf;
      ushort8 b0 = *(const ushort8*)b, b1 = *(const ushort8*)(b+8);
      *(ushort8*)&As[srow][shalf] = a0; *(ushort8*)&As[srow][shalf+8] = a1;
      *(ushort8*)&Bs[srow][shalf] = b0; *(ushort8*)&Bs[srow][shalf+8] = b1;
    }
    __syncthreads();
    bf16x8 af[4], bfr[4];
#pragma unroll
    for (int i = 0; i < 4; ++i){
      af[i]  = *(const bf16x8*)&As[wr*64 + i*16 + lr][lg*8];
      bfr[i] = *(const bf16x8*)&Bs[wc*64 + i*16 + lr][lg*8];
    }
#pragma unroll
    for (int i = 0; i < 4; ++i)
#pragma unroll
      for (int j = 0; j < 4; ++j)
        acc[i][j] = MFMA16(af[i], bfr[j], acc[i][j]);
    __syncthreads();
  }
#pragma unroll
  for (int i = 0; i < 4; ++i){
    const int row = m0 + wr*64 + i*16 + lg*4;
#pragma unroll
    for (int j = 0; j < 4; ++j){
      const int col = wc*64 + j*16 + lr;
      const float bias = fcb[col];
#pragma unroll
      for (int r = 0; r < 4; ++r)
        out[(size_t)(row + r)*NV + col] = acc[i][j][r] + bias;
    }
  }
}

extern "C" void kernel_launch(void* const* d_in, const int* in_sizes, int n_in,
                              void* d_out, int out_size, void* d_ws, size_t ws_size,
                              hipStream_t stream)
{
  const int*   x   = (const int*)  d_in[0];
  const float* emb = (const float*)d_in[1];
  const float* wxw = (const float*)d_in[2];
  const float* wxb = (const float*)d_in[3];
  const float* whw = (const float*)d_in[4];
  const float* whb = (const float*)d_in[5];
  const float* waw = (const float*)d_in[6];
  const float* wab = (const float*)d_in[7];
  const float* fcw = (const float*)d_in[8];
  const float* fcb = (const float*)d_in[9];
  float* out = (float*)d_out;

  char* ws = (char*)d_ws;
  unsigned int* cnt = (unsigned int*)(ws);            // 4 KB
  float* hstate = (float*)(ws + 4096);                // 256 KB
  float* XW     = (float*)(ws + 266240);              // 512 KB
  u16*   Harc   = (u16*)  (ws + 790528);              // 64 MB  H archive (bf16)
  u16*   Aarc   = (u16*)  (ws + 67899392);            // 64 MB  A archive; later reused as Ctx
  u16*   SW     = (u16*)  (ws + 135008256);           // 64 MB  scores/weights (in place)
  u16*   wa_bf  = (u16*)  (ws + 135008256);           // aliases SW[0:2MB] (dead before scores)
  u16*   fc_bf  = (u16*)  (ws + 202117120);           // 512 KB  -> total ~202.6 MB
  u16*   Ctx    = Aarc;                               // PV output overwrites A archive

  (void)hipMemsetAsync(ws, 0, 266240, stream);        // cnt + hstate zeros

  k_cvt<<<dim3(5120), dim3(256), 0, stream>>>(waw, fcw, wa_bf, fc_bf);
  k_xw<<<dim3(NV), dim3(256), 0, stream>>>(emb, wxw, wxb, XW);

  {
    void* args[] = { (void*)&x, (void*)&whw, (void*)&whb, (void*)&XW,
                     (void*)&hstate, (void*)&Harc, (void*)&cnt };
    (void)hipLaunchCooperativeKernel((const void*)k_scan2, dim3(256), dim3(256),
                                     args, 0, stream);
  }

  k_gemm_A<<<dim3(256, 8), dim3(256), 0, stream>>>(Harc, wa_bf, wab, Aarc);
  k_scores<<<dim3(8, 8, 32), dim3(256), 0, stream>>>(Harc, Aarc, SW);
  k_softmax<<<dim3(32768), dim3(256), 0, stream>>>(SW);
  k_pv<<<dim3(8, 8, 32), dim3(256), 0, stream>>>(SW, Harc, Ctx);
  k_out2<<<dim3(256), dim3(256), 0, stream>>>(Harc, Ctx, fc_bf, fcb, out);
}

// Round 5
// 7044.784 us; speedup vs baseline: 5.4902x; 1.7015x over previous
//
#include <hip/hip_runtime.h>
#include <hip/hip_bf16.h>
#include <hip/hip_cooperative_groups.h>

#define NV 128
#define NE 256
#define HD 1024
#define NB 32
#define NS 1024

typedef unsigned short u16;
typedef unsigned short ushort8 __attribute__((ext_vector_type(8)));
typedef unsigned short u16x4 __attribute__((ext_vector_type(4)));
typedef short bf16x8 __attribute__((ext_vector_type(8)));
typedef float f32x4 __attribute__((ext_vector_type(4)));

#define MFMA16(a, b, c) __builtin_amdgcn_mfma_f32_16x16x32_bf16(a, b, c, 0, 0, 0)

__device__ __forceinline__ float bf2f(u16 u){
  unsigned int x = ((unsigned int)u) << 16;
  return __builtin_bit_cast(float, x);
}
__device__ __forceinline__ u16 f2bf(float f){
  unsigned int u = __builtin_bit_cast(unsigned int, f);
  unsigned int r = u + 0x7fffu + ((u >> 16) & 1u);
  return (u16)(r >> 16);
}

// ---------------- K0: fp32 weights -> bf16 copies ----------------
__global__ __launch_bounds__(256) void k_cvt(const float* __restrict__ waw,
    const float* __restrict__ fcw, u16* __restrict__ wa_bf, u16* __restrict__ fc_bf)
{
  const int i = blockIdx.x * 256 + threadIdx.x;
  if (i < 1048576) wa_bf[i] = f2bf(waw[i]);
  const int j = i - 1048576;
  if (j >= 0 && j < 262144) fc_bf[j] = f2bf(fcw[j]);
}

// ---------------- K1: XW[v,h] = sum_e emb[v,e]*Wx[h,e] + Wx_b[h] ----------------
__global__ __launch_bounds__(256) void k_xw(const float* __restrict__ emb,
    const float* __restrict__ wxw, const float* __restrict__ wxb,
    float* __restrict__ XW)
{
  __shared__ float es[NE];
  const int v = blockIdx.x;
  for (int i = threadIdx.x; i < NE; i += 256) es[i] = emb[v*NE + i];
  __syncthreads();
  for (int h = threadIdx.x; h < HD; h += 256){
    const float* wr = wxw + (size_t)h * NE;
    float acc = 0.f;
#pragma unroll 4
    for (int e = 0; e < NE; e += 4){
      float4 w4 = *reinterpret_cast<const float4*>(wr + e);
      acc += w4.x*es[e] + w4.y*es[e+1] + w4.z*es[e+2] + w4.w*es[e+3];
    }
    XW[(size_t)v*HD + h] = acc + wxb[h];
  }
}

// ---------------- K2: RNN scan, per-batch-group barriers ----------------
// h exchange goes WRITE-THROUGH to Infinity Cache (relaxed agent atomics, sc1):
// no dirty-L2 flush (buffer_wbl2) and no per-poll invalidate (buffer_inv) —
// exactly one acquire fence per step, issued by tid0 after the flag trips.
__global__ __launch_bounds__(256, 1) void k_scan2(const int* __restrict__ x,
    const float* __restrict__ whw, const float* __restrict__ whb,
    const float* __restrict__ XW, float* __restrict__ hstate,
    u16* __restrict__ Harc, unsigned int* __restrict__ cnt)
{
  __shared__ __align__(16) float hs[4096];
  __shared__ int xs[4096];
  const int tid = threadIdx.x;
  const int g = blockIdx.x & 7;
  const int m = blockIdx.x >> 3;
  const int c = tid & 7;
  const int rp = tid >> 3;
  const int row = m*32 + rp;

  for (int i = tid; i < 4096; i += 256) xs[i] = x[g*4096 + i];

  float4 wv[32];
#pragma unroll
  for (int j = 0; j < 32; ++j){
    const int k = (4*(j + c)) & 127;
    wv[j] = *reinterpret_cast<const float4*>(whw + (size_t)row*HD + c*128 + k);
  }
  const float bias = whb[row];
  unsigned int* bar = cnt + g*32;
  __syncthreads();

  for (int t = 0; t < NS; ++t){
    const float* hin  = hstate + (size_t)(t & 1)*(NB*HD) + g*4*HD;
    float*       hout = hstate + (size_t)((t & 1)^1)*(NB*HD) + g*4*HD;
#pragma unroll
    for (int q = 0; q < 4; ++q)
      *reinterpret_cast<float4*>(&hs[q*1024 + tid*4]) =
        *reinterpret_cast<const float4*>(hin + q*1024 + tid*4);
    int xv = 0; float xwv = 0.f;
    if (c < 4){
      xv  = xs[c*1024 + t];
      xwv = XW[(size_t)xv*HD + row];
    }
    __syncthreads();
    float s0=0.f, s1=0.f, s2=0.f, s3=0.f;
#pragma unroll
    for (int j = 0; j < 32; ++j){
      const int k = c*128 + ((4*(j + c)) & 127);
      float4 h0 = *reinterpret_cast<const float4*>(&hs[k]);
      float4 h1 = *reinterpret_cast<const float4*>(&hs[1024 + k]);
      float4 h2 = *reinterpret_cast<const float4*>(&hs[2048 + k]);
      float4 h3 = *reinterpret_cast<const float4*>(&hs[3072 + k]);
      s0 += wv[j].x*h0.x + wv[j].y*h0.y + wv[j].z*h0.z + wv[j].w*h0.w;
      s1 += wv[j].x*h1.x + wv[j].y*h1.y + wv[j].z*h1.z + wv[j].w*h1.w;
      s2 += wv[j].x*h2.x + wv[j].y*h2.y + wv[j].z*h2.z + wv[j].w*h2.w;
      s3 += wv[j].x*h3.x + wv[j].y*h3.y + wv[j].z*h3.z + wv[j].w*h3.w;
    }
#pragma unroll
    for (int mm = 1; mm <= 4; mm <<= 1){
      s0 += __shfl_xor(s0, mm);
      s1 += __shfl_xor(s1, mm);
      s2 += __shfl_xor(s2, mm);
      s3 += __shfl_xor(s3, mm);
    }
    if (c < 4){
      const float sv = (c==0) ? s0 : (c==1) ? s1 : (c==2) ? s2 : s3;
      const float val = tanhf(xwv + bias + sv);
      // write-through (sc1) store: IC-visible once vmcnt drains, no L2 dirty line
      __hip_atomic_store(&hout[c*HD + row], val, __ATOMIC_RELAXED,
                         __HIP_MEMORY_SCOPE_AGENT);
      Harc[(((size_t)(g*4 + c))*NS + t)*HD + row] = f2bf(val);
    }
    __syncthreads();   // per-wave vmcnt(0) before s_barrier: h stores are IC-visible
    if (tid == 0){
      __hip_atomic_fetch_add(bar, 1u, __ATOMIC_RELAXED, __HIP_MEMORY_SCOPE_AGENT);
      const unsigned int target = 32u*(unsigned)(t+1);
      while (__hip_atomic_load(bar, __ATOMIC_RELAXED, __HIP_MEMORY_SCOPE_AGENT) < target)
        __builtin_amdgcn_s_sleep(1);
      __builtin_amdgcn_fence(__ATOMIC_ACQUIRE, "agent");  // one L1/L2 inv per step
    }
    __syncthreads();
  }
}

// ---------------- K3: A = H @ Wa^T + b  (MFMA, 128x128 tile) ----------------
__global__ __launch_bounds__(256) void k_gemm_A(const u16* __restrict__ Harc,
    const u16* __restrict__ wa_bf, const float* __restrict__ wab,
    u16* __restrict__ Aarc)
{
  __shared__ u16 As[128][40];
  __shared__ u16 Bs[128][40];
  const int tid = threadIdx.x;
  const int m0 = blockIdx.x * 128;
  const int n0 = blockIdx.y * 128;
  const int l = tid & 63, w = tid >> 6;
  const int wr = w >> 1, wc = w & 1;
  const int lr = l & 15, lg = l >> 4;
  const int srow = tid >> 1, shalf = (tid & 1) * 16;
  f32x4 acc[4][4] = {};
  for (int k0 = 0; k0 < 1024; k0 += 32){
    {
      const u16* a = Harc + (size_t)(m0 + srow)*HD + k0 + shalf;
      ushort8 a0 = *(const ushort8*)a, a1 = *(const ushort8*)(a+8);
      const u16* b = wa_bf + (size_t)(n0 + srow)*HD + k0 + shalf;
      ushort8 b0 = *(const ushort8*)b, b1 = *(const ushort8*)(b+8);
      *(ushort8*)&As[srow][shalf] = a0; *(ushort8*)&As[srow][shalf+8] = a1;
      *(ushort8*)&Bs[srow][shalf] = b0; *(ushort8*)&Bs[srow][shalf+8] = b1;
    }
    __syncthreads();
    bf16x8 af[4], bfr[4];
#pragma unroll
    for (int i = 0; i < 4; ++i){
      af[i]  = *(const bf16x8*)&As[wr*64 + i*16 + lr][lg*8];
      bfr[i] = *(const bf16x8*)&Bs[wc*64 + i*16 + lr][lg*8];
    }
#pragma unroll
    for (int i = 0; i < 4; ++i)
#pragma unroll
      for (int j = 0; j < 4; ++j)
        acc[i][j] = MFMA16(af[i], bfr[j], acc[i][j]);
    __syncthreads();
  }
#pragma unroll
  for (int i = 0; i < 4; ++i){
    const int row = m0 + wr*64 + i*16 + lg*4;
#pragma unroll
    for (int j = 0; j < 4; ++j){
      const int col = n0 + wc*64 + j*16 + lr;
      const float bias = wab[col];
#pragma unroll
      for (int r = 0; r < 4; ++r)
        Aarc[(size_t)(row + r)*HD + col] = f2bf(acc[i][j][r] + bias);
    }
  }
}

// ---------------- K4a: S[b,t,s] = H[b,t]·A[b,s]  (causal tiles only) ----------------
__global__ __launch_bounds__(256) void k_scores(const u16* __restrict__ Harc,
    const u16* __restrict__ Aarc, u16* __restrict__ SW)
{
  if (blockIdx.x > blockIdx.y) return;   // s-tile beyond t-tile: never read
  __shared__ u16 As[128][40];
  __shared__ u16 Bs[128][40];
  const int tid = threadIdx.x;
  const int bz = blockIdx.z;
  const int m0 = blockIdx.y * 128;   // t
  const int n0 = blockIdx.x * 128;   // s
  const u16* Hb = Harc + (size_t)bz * NS * HD;
  const u16* Ab = Aarc + (size_t)bz * NS * HD;
  u16* Sb = SW + ((size_t)bz << 20);
  const int l = tid & 63, w = tid >> 6;
  const int wr = w >> 1, wc = w & 1;
  const int lr = l & 15, lg = l >> 4;
  const int srow = tid >> 1, shalf = (tid & 1) * 16;
  f32x4 acc[4][4] = {};
  for (int k0 = 0; k0 < 1024; k0 += 32){
    {
      const u16* a = Hb + (size_t)(m0 + srow)*HD + k0 + shalf;
      ushort8 a0 = *(const ushort8*)a, a1 = *(const ushort8*)(a+8);
      const u16* b = Ab + (size_t)(n0 + srow)*HD + k0 + shalf;
      ushort8 b0 = *(const ushort8*)b, b1 = *(const ushort8*)(b+8);
      *(ushort8*)&As[srow][shalf] = a0; *(ushort8*)&As[srow][shalf+8] = a1;
      *(ushort8*)&Bs[srow][shalf] = b0; *(ushort8*)&Bs[srow][shalf+8] = b1;
    }
    __syncthreads();
    bf16x8 af[4], bfr[4];
#pragma unroll
    for (int i = 0; i < 4; ++i){
      af[i]  = *(const bf16x8*)&As[wr*64 + i*16 + lr][lg*8];
      bfr[i] = *(const bf16x8*)&Bs[wc*64 + i*16 + lr][lg*8];
    }
#pragma unroll
    for (int i = 0; i < 4; ++i)
#pragma unroll
      for (int j = 0; j < 4; ++j)
        acc[i][j] = MFMA16(af[i], bfr[j], acc[i][j]);
    __syncthreads();
  }
#pragma unroll
  for (int i = 0; i < 4; ++i){
    const int row = m0 + wr*64 + i*16 + lg*4;
#pragma unroll
    for (int j = 0; j < 4; ++j){
      const int col = n0 + wc*64 + j*16 + lr;
#pragma unroll
      for (int r = 0; r < 4; ++r)
        Sb[((size_t)(row + r) << 10) + col] = f2bf(acc[i][j][r]);
    }
  }
}

// ---------------- K4b: row softmax over s (in place, zero-fill s>t) ----------------
__global__ __launch_bounds__(256) void k_softmax(u16* __restrict__ SW)
{
  const int bid = blockIdx.x;
  const int b = bid >> 10, t = bid & 1023;
  u16* row = SW + ((size_t)b << 20) + ((size_t)t << 10);
  const int i0 = threadIdx.x * 4;
  u16x4 v = *(const u16x4*)(row + i0);
  float x[4];
#pragma unroll
  for (int j = 0; j < 4; ++j) x[j] = (i0 + j <= t) ? bf2f(v[j]) : -1e30f;
  float m = fmaxf(fmaxf(x[0], x[1]), fmaxf(x[2], x[3]));
#pragma unroll
  for (int o = 1; o < 64; o <<= 1) m = fmaxf(m, __shfl_xor(m, o));
  __shared__ float redm[4], reds[4];
  if ((threadIdx.x & 63) == 0) redm[threadIdx.x >> 6] = m;
  __syncthreads();
  m = fmaxf(fmaxf(redm[0], redm[1]), fmaxf(redm[2], redm[3]));
  float e[4]; float s = 0.f;
#pragma unroll
  for (int j = 0; j < 4; ++j){ e[j] = __expf(x[j] - m); s += e[j]; }
#pragma unroll
  for (int o = 1; o < 64; o <<= 1) s += __shfl_xor(s, o);
  if ((threadIdx.x & 63) == 0) reds[threadIdx.x >> 6] = s;
  __syncthreads();
  s = reds[0] + reds[1] + reds[2] + reds[3];
  const float inv = 1.f / s;
  u16x4 o4;
#pragma unroll
  for (int j = 0; j < 4; ++j) o4[j] = f2bf(e[j] * inv);
  *(u16x4*)(row + i0) = o4;
}

// ---------------- K4c: Ctx[b,t,e] = sum_s W[b,t,s] * H[b,s,e] ----------------
__global__ __launch_bounds__(256) void k_pv(const u16* __restrict__ SW,
    const u16* __restrict__ Harc, u16* __restrict__ Ctx)
{
  __shared__ u16 As[128][40];   // W rows t, cols s
  __shared__ u16 Bs[128][40];   // H^T rows e, cols s
  const int tid = threadIdx.x;
  const int bz = blockIdx.z;
  const int t0 = blockIdx.x * 128;
  const int e0 = blockIdx.y * 128;
  const u16* Wb = SW + ((size_t)bz << 20);
  const u16* Hb = Harc + (size_t)bz * NS * HD;
  u16* Cb = Ctx + (size_t)bz * NS * HD;
  const int l = tid & 63, w = tid >> 6;
  const int wr = w >> 1, wc = w & 1;
  const int lr = l & 15, lg = l >> 4;
  const int srow = tid >> 1, shalf = (tid & 1) * 16;
  const int sIdx = tid & 31, ec = tid >> 5;
  const int ksteps = (blockIdx.x + 1) * 4;    // s < t0 + 128 (causal bound)
  f32x4 acc[4][4] = {};
  for (int ks = 0; ks < ksteps; ++ks){
    const int k0 = ks * 32;
    {
      const u16* a = Wb + ((size_t)(t0 + srow) << 10) + k0 + shalf;
      ushort8 a0 = *(const ushort8*)a, a1 = *(const ushort8*)(a+8);
      const u16* b = Hb + (size_t)(k0 + sIdx)*HD + e0 + ec*16;
      ushort8 b0 = *(const ushort8*)b, b1 = *(const ushort8*)(b+8);
      *(ushort8*)&As[srow][shalf] = a0; *(ushort8*)&As[srow][shalf+8] = a1;
#pragma unroll
      for (int i = 0; i < 8; ++i){
        Bs[ec*16 + i][sIdx] = b0[i];
        Bs[ec*16 + 8 + i][sIdx] = b1[i];
      }
    }
    __syncthreads();
    bf16x8 af[4], bfr[4];
#pragma unroll
    for (int i = 0; i < 4; ++i){
      af[i]  = *(const bf16x8*)&As[wr*64 + i*16 + lr][lg*8];
      bfr[i] = *(const bf16x8*)&Bs[wc*64 + i*16 + lr][lg*8];
    }
#pragma unroll
    for (int i = 0; i < 4; ++i)
#pragma unroll
      for (int j = 0; j < 4; ++j)
        acc[i][j] = MFMA16(af[i], bfr[j], acc[i][j]);
    __syncthreads();
  }
#pragma unroll
  for (int i = 0; i < 4; ++i){
    const int row = t0 + wr*64 + i*16 + lg*4;
#pragma unroll
    for (int j = 0; j < 4; ++j){
      const int col = e0 + wc*64 + j*16 + lr;
#pragma unroll
      for (int r = 0; r < 4; ++r)
        Cb[(size_t)(row + r)*HD + col] = f2bf(acc[i][j][r]);
    }
  }
}

// ---------------- K5: out = [H|ctx] @ fc^T + b  (MFMA, N=128) ----------------
__global__ __launch_bounds__(256) void k_out2(const u16* __restrict__ Harc,
    const u16* __restrict__ Ctx, const u16* __restrict__ fc_bf,
    const float* __restrict__ fcb, float* __restrict__ out)
{
  __shared__ u16 As[128][40];
  __shared__ u16 Bs[128][40];
  const int tid = threadIdx.x;
  const int m0 = blockIdx.x * 128;
  const int l = tid & 63, w = tid >> 6;
  const int wr = w >> 1, wc = w & 1;
  const int lr = l & 15, lg = l >> 4;
  const int srow = tid >> 1, shalf = (tid & 1) * 16;
  f32x4 acc[4][4] = {};
  for (int k0 = 0; k0 < 2048; k0 += 32){
    {
      const u16* abase = (k0 < 1024) ? Harc : Ctx;
      const u16* a = abase + (size_t)(m0 + srow)*HD + (k0 & 1023) + shalf;
      ushort8 a0 = *(const ushort8*)a, a1 = *(const ushort8*)(a+8);
      const u16* b = fc_bf + (size_t)srow*2048 + k0 + shalf;
      ushort8 b0 = *(const ushort8*)b, b1 = *(const ushort8*)(b+8);
      *(ushort8*)&As[srow][shalf] = a0; *(ushort8*)&As[srow][shalf+8] = a1;
      *(ushort8*)&Bs[srow][shalf] = b0; *(ushort8*)&Bs[srow][shalf+8] = b1;
    }
    __syncthreads();
    bf16x8 af[4], bfr[4];
#pragma unroll
    for (int i = 0; i < 4; ++i){
      af[i]  = *(const bf16x8*)&As[wr*64 + i*16 + lr][lg*8];
      bfr[i] = *(const bf16x8*)&Bs[wc*64 + i*16 + lr][lg*8];
    }
#pragma unroll
    for (int i = 0; i < 4; ++i)
#pragma unroll
      for (int j = 0; j < 4; ++j)
        acc[i][j] = MFMA16(af[i], bfr[j], acc[i][j]);
    __syncthreads();
  }
#pragma unroll
  for (int i = 0; i < 4; ++i){
    const int row = m0 + wr*64 + i*16 + lg*4;
#pragma unroll
    for (int j = 0; j < 4; ++j){
      const int col = wc*64 + j*16 + lr;
      const float bias = fcb[col];
#pragma unroll
      for (int r = 0; r < 4; ++r)
        out[(size_t)(row + r)*NV + col] = acc[i][j][r] + bias;
    }
  }
}

extern "C" void kernel_launch(void* const* d_in, const int* in_sizes, int n_in,
                              void* d_out, int out_size, void* d_ws, size_t ws_size,
                              hipStream_t stream)
{
  const int*   x   = (const int*)  d_in[0];
  const float* emb = (const float*)d_in[1];
  const float* wxw = (const float*)d_in[2];
  const float* wxb = (const float*)d_in[3];
  const float* whw = (const float*)d_in[4];
  const float* whb = (const float*)d_in[5];
  const float* waw = (const float*)d_in[6];
  const float* wab = (const float*)d_in[7];
  const float* fcw = (const float*)d_in[8];
  const float* fcb = (const float*)d_in[9];
  float* out = (float*)d_out;

  char* ws = (char*)d_ws;
  unsigned int* cnt = (unsigned int*)(ws);            // 4 KB
  float* hstate = (float*)(ws + 4096);                // 256 KB
  float* XW     = (float*)(ws + 266240);              // 512 KB
  u16*   Harc   = (u16*)  (ws + 790528);              // 64 MB  H archive (bf16)
  u16*   Aarc   = (u16*)  (ws + 67899392);            // 64 MB  A archive; later reused as Ctx
  u16*   SW     = (u16*)  (ws + 135008256);           // 64 MB  scores/weights (in place)
  u16*   wa_bf  = (u16*)  (ws + 135008256);           // aliases SW[0:2MB] (dead before scores)
  u16*   fc_bf  = (u16*)  (ws + 202117120);           // 512 KB  -> total ~202.6 MB
  u16*   Ctx    = Aarc;                               // PV output overwrites A archive

  (void)hipMemsetAsync(ws, 0, 266240, stream);        // cnt + hstate zeros

  k_cvt<<<dim3(5120), dim3(256), 0, stream>>>(waw, fcw, wa_bf, fc_bf);
  k_xw<<<dim3(NV), dim3(256), 0, stream>>>(emb, wxw, wxb, XW);

  {
    void* args[] = { (void*)&x, (void*)&whw, (void*)&whb, (void*)&XW,
                     (void*)&hstate, (void*)&Harc, (void*)&cnt };
    (void)hipLaunchCooperativeKernel((const void*)k_scan2, dim3(256), dim3(256),
                                     args, 0, stream);
  }

  k_gemm_A<<<dim3(256, 8), dim3(256), 0, stream>>>(Harc, wa_bf, wab, Aarc);
  k_scores<<<dim3(8, 8, 32), dim3(256), 0, stream>>>(Harc, Aarc, SW);
  k_softmax<<<dim3(32768), dim3(256), 0, stream>>>(SW);
  k_pv<<<dim3(8, 8, 32), dim3(256), 0, stream>>>(SW, Harc, Ctx);
  k_out2<<<dim3(256), dim3(256), 0, stream>>>(Harc, Ctx, fc_bf, fcb, out);
}

// Round 7
// 6551.280 us; speedup vs baseline: 5.9038x; 1.0753x over previous
//
#include <hip/hip_runtime.h>
#include <hip/hip_bf16.h>
#include <hip/hip_cooperative_groups.h>

#define NV 128
#define NE 256
#define HD 1024
#define NB 32
#define NS 1024

typedef unsigned short u16;
typedef unsigned short ushort8 __attribute__((ext_vector_type(8)));
typedef unsigned short u16x4 __attribute__((ext_vector_type(4)));
typedef short bf16x8 __attribute__((ext_vector_type(8)));
typedef float f32x4 __attribute__((ext_vector_type(4)));

#define MFMA16(a, b, c) __builtin_amdgcn_mfma_f32_16x16x32_bf16(a, b, c, 0, 0, 0)

__device__ __forceinline__ float bf2f(u16 u){
  unsigned int x = ((unsigned int)u) << 16;
  return __builtin_bit_cast(float, x);
}
__device__ __forceinline__ u16 f2bf(float f){
  unsigned int u = __builtin_bit_cast(unsigned int, f);
  unsigned int r = u + 0x7fffu + ((u >> 16) & 1u);
  return (u16)(r >> 16);
}

// ---------------- K0: fp32 weights -> bf16 copies ----------------
__global__ __launch_bounds__(256) void k_cvt(const float* __restrict__ waw,
    const float* __restrict__ fcw, u16* __restrict__ wa_bf, u16* __restrict__ fc_bf)
{
  const int i = blockIdx.x * 256 + threadIdx.x;
  if (i < 1048576) wa_bf[i] = f2bf(waw[i]);
  const int j = i - 1048576;
  if (j >= 0 && j < 262144) fc_bf[j] = f2bf(fcw[j]);
}

// ---------------- K1: XW[v,h] = sum_e emb[v,e]*Wx[h,e] + Wx_b[h] ----------------
__global__ __launch_bounds__(256) void k_xw(const float* __restrict__ emb,
    const float* __restrict__ wxw, const float* __restrict__ wxb,
    float* __restrict__ XW)
{
  __shared__ float es[NE];
  const int v = blockIdx.x;
  for (int i = threadIdx.x; i < NE; i += 256) es[i] = emb[v*NE + i];
  __syncthreads();
  for (int h = threadIdx.x; h < HD; h += 256){
    const float* wr = wxw + (size_t)h * NE;
    float acc = 0.f;
#pragma unroll 4
    for (int e = 0; e < NE; e += 4){
      float4 w4 = *reinterpret_cast<const float4*>(wr + e);
      acc += w4.x*es[e] + w4.y*es[e+1] + w4.z*es[e+2] + w4.w*es[e+3];
    }
    XW[(size_t)v*HD + h] = acc + wxb[h];
  }
}

// ---------------- K2: RNN scan ----------------
// R5 structure + barrier VERBATIM (proven); only the per-thread work tiling
// changed: R=4 rows x K=32 k-slice (kc = tid&31, rg = tid>>5), cutting LDS
// reads 4x (MAC:LDS = 4:1). Reduction: 5-level shfl_xor within the 32-lane
// kc-half, then a local equality-chain select (all lanes hold all 16 sums).
__global__ __launch_bounds__(256, 2) void k_scan2(const int* __restrict__ x,
    const float* __restrict__ whw, const float* __restrict__ whb,
    const float* __restrict__ XW, float* __restrict__ hstate,
    u16* __restrict__ Harc, unsigned int* __restrict__ cnt)
{
  __shared__ __align__(16) float hs[4096];   // 4 batches x 1024
  __shared__ int xs[4096];                   // 4 batches x 1024 token ids
  const int tid = threadIdx.x;
  const int g = blockIdx.x & 7;
  const int m = blockIdx.x >> 3;
  const int kc = tid & 31;
  const int rg = tid >> 5;
  const int row0 = m*32 + rg*4;

  for (int i = tid; i < 4096; i += 256) xs[i] = x[g*4096 + i];

  // Wh fragments: 4 rows x 32 k (8 float4), k-rotated to spread LDS banks
  float4 wv[4][8];
#pragma unroll
  for (int r = 0; r < 4; ++r)
#pragma unroll
    for (int j = 0; j < 8; ++j)
      wv[r][j] = *reinterpret_cast<const float4*>(
          whw + (size_t)(row0 + r)*HD + kc*32 + ((4*(j + kc)) & 31));

  // lane kc<16 of each rg writes (row rr, batch bb)
  const int rr = row0 + (kc & 3);
  const int bb = kc >> 2;
  const float bias = whb[rr];
  unsigned int* bar = cnt + g*32;            // 128B-padded per-group counter
  __syncthreads();                           // xs ready

  for (int t = 0; t < NS; ++t){
    const float* hin  = hstate + (size_t)(t & 1)*(NB*HD) + g*4*HD;
    float*       hout = hstate + (size_t)((t & 1)^1)*(NB*HD) + g*4*HD;
    // stage 4 batch rows of h (16 KB), coalesced (buffer 0 pre-zeroed for t=0)
#pragma unroll
    for (int q = 0; q < 4; ++q)
      *reinterpret_cast<float4*>(&hs[q*1024 + tid*4]) =
        *reinterpret_cast<const float4*>(hin + q*1024 + tid*4);
    // prefetch per-step gather operand (hide IC latency under FMAs)
    float xwv = 0.f;
    if (kc < 16){
      const int xv = xs[bb*1024 + t];
      xwv = XW[(size_t)xv*HD + rr];
    }
    __syncthreads();

    float acc[4][4] = {};   // [row r][batch b]
#pragma unroll
    for (int j = 0; j < 8; ++j){
      const int off = kc*32 + ((4*(j + kc)) & 31);
      float4 h4[4];
#pragma unroll
      for (int b = 0; b < 4; ++b)
        h4[b] = *reinterpret_cast<const float4*>(&hs[b*1024 + off]);
#pragma unroll
      for (int r = 0; r < 4; ++r)
#pragma unroll
        for (int b = 0; b < 4; ++b)
          acc[r][b] += wv[r][j].x*h4[b].x + wv[r][j].y*h4[b].y
                     + wv[r][j].z*h4[b].z + wv[r][j].w*h4[b].w;
    }
    // butterfly reduce across the 32 kc-lanes (stays within each 32-lane half)
#pragma unroll
    for (int mm = 1; mm <= 16; mm <<= 1)
#pragma unroll
      for (int r = 0; r < 4; ++r)
#pragma unroll
        for (int b = 0; b < 4; ++b)
          acc[r][b] += __shfl_xor(acc[r][b], mm);
    // all lanes now hold all 16 totals; lane kc<16 takes acc[kc&3][kc>>2]
    float sv = acc[0][0];
#pragma unroll
    for (int r = 0; r < 4; ++r)
#pragma unroll
      for (int b = 0; b < 4; ++b)
        if ((kc & 15) == b*4 + r) sv = acc[r][b];

    if (kc < 16){
      const float val = tanhf(xwv + bias + sv);
      // write-through store: IC-visible after vmcnt drain, no dirty L2 line
      __hip_atomic_store(&hout[bb*HD + rr], val, __ATOMIC_RELAXED,
                         __HIP_MEMORY_SCOPE_AGENT);
      Harc[(((size_t)(g*4 + bb))*NS + t)*HD + rr] = f2bf(val);
    }
    __syncthreads();   // per-wave vmcnt(0) before s_barrier: stores visible
    if (tid == 0){
      __hip_atomic_fetch_add(bar, 1u, __ATOMIC_RELAXED, __HIP_MEMORY_SCOPE_AGENT);
      const unsigned int target = 32u*(unsigned)(t+1);
      while (__hip_atomic_load(bar, __ATOMIC_RELAXED, __HIP_MEMORY_SCOPE_AGENT) < target)
        __builtin_amdgcn_s_sleep(1);
      __builtin_amdgcn_fence(__ATOMIC_ACQUIRE, "agent");  // one L1/L2 inv per step
    }
    __syncthreads();
  }
}

// ---------------- K3: A = H @ Wa^T + b  (MFMA, 128x128 tile) ----------------
__global__ __launch_bounds__(256) void k_gemm_A(const u16* __restrict__ Harc,
    const u16* __restrict__ wa_bf, const float* __restrict__ wab,
    u16* __restrict__ Aarc)
{
  __shared__ u16 As[128][40];
  __shared__ u16 Bs[128][40];
  const int tid = threadIdx.x;
  const int m0 = blockIdx.x * 128;
  const int n0 = blockIdx.y * 128;
  const int l = tid & 63, w = tid >> 6;
  const int wr = w >> 1, wc = w & 1;
  const int lr = l & 15, lg = l >> 4;
  const int srow = tid >> 1, shalf = (tid & 1) * 16;
  f32x4 acc[4][4] = {};
  for (int k0 = 0; k0 < 1024; k0 += 32){
    {
      const u16* a = Harc + (size_t)(m0 + srow)*HD + k0 + shalf;
      ushort8 a0 = *(const ushort8*)a, a1 = *(const ushort8*)(a+8);
      const u16* b = wa_bf + (size_t)(n0 + srow)*HD + k0 + shalf;
      ushort8 b0 = *(const ushort8*)b, b1 = *(const ushort8*)(b+8);
      *(ushort8*)&As[srow][shalf] = a0; *(ushort8*)&As[srow][shalf+8] = a1;
      *(ushort8*)&Bs[srow][shalf] = b0; *(ushort8*)&Bs[srow][shalf+8] = b1;
    }
    __syncthreads();
    bf16x8 af[4], bfr[4];
#pragma unroll
    for (int i = 0; i < 4; ++i){
      af[i]  = *(const bf16x8*)&As[wr*64 + i*16 + lr][lg*8];
      bfr[i] = *(const bf16x8*)&Bs[wc*64 + i*16 + lr][lg*8];
    }
#pragma unroll
    for (int i = 0; i < 4; ++i)
#pragma unroll
      for (int j = 0; j < 4; ++j)
        acc[i][j] = MFMA16(af[i], bfr[j], acc[i][j]);
    __syncthreads();
  }
#pragma unroll
  for (int i = 0; i < 4; ++i){
    const int row = m0 + wr*64 + i*16 + lg*4;
#pragma unroll
    for (int j = 0; j < 4; ++j){
      const int col = n0 + wc*64 + j*16 + lr;
      const float bias = wab[col];
#pragma unroll
      for (int r = 0; r < 4; ++r)
        Aarc[(size_t)(row + r)*HD + col] = f2bf(acc[i][j][r] + bias);
    }
  }
}

// ---------------- K4a: S[b,t,s] = H[b,t]·A[b,s]  (causal tiles only) ----------------
__global__ __launch_bounds__(256) void k_scores(const u16* __restrict__ Harc,
    const u16* __restrict__ Aarc, u16* __restrict__ SW)
{
  if (blockIdx.x > blockIdx.y) return;   // s-tile beyond t-tile: never read
  __shared__ u16 As[128][40];
  __shared__ u16 Bs[128][40];
  const int tid = threadIdx.x;
  const int bz = blockIdx.z;
  const int m0 = blockIdx.y * 128;   // t
  const int n0 = blockIdx.x * 128;   // s
  const u16* Hb = Harc + (size_t)bz * NS * HD;
  const u16* Ab = Aarc + (size_t)bz * NS * HD;
  u16* Sb = SW + ((size_t)bz << 20);
  const int l = tid & 63, w = tid >> 6;
  const int wr = w >> 1, wc = w & 1;
  const int lr = l & 15, lg = l >> 4;
  const int srow = tid >> 1, shalf = (tid & 1) * 16;
  f32x4 acc[4][4] = {};
  for (int k0 = 0; k0 < 1024; k0 += 32){
    {
      const u16* a = Hb + (size_t)(m0 + srow)*HD + k0 + shalf;
      ushort8 a0 = *(const ushort8*)a, a1 = *(const ushort8*)(a+8);
      const u16* b = Ab + (size_t)(n0 + srow)*HD + k0 + shalf;
      ushort8 b0 = *(const ushort8*)b, b1 = *(const ushort8*)(b+8);
      *(ushort8*)&As[srow][shalf] = a0; *(ushort8*)&As[srow][shalf+8] = a1;
      *(ushort8*)&Bs[srow][shalf] = b0; *(ushort8*)&Bs[srow][shalf+8] = b1;
    }
    __syncthreads();
    bf16x8 af[4], bfr[4];
#pragma unroll
    for (int i = 0; i < 4; ++i){
      af[i]  = *(const bf16x8*)&As[wr*64 + i*16 + lr][lg*8];
      bfr[i] = *(const bf16x8*)&Bs[wc*64 + i*16 + lr][lg*8];
    }
#pragma unroll
    for (int i = 0; i < 4; ++i)
#pragma unroll
      for (int j = 0; j < 4; ++j)
        acc[i][j] = MFMA16(af[i], bfr[j], acc[i][j]);
    __syncthreads();
  }
#pragma unroll
  for (int i = 0; i < 4; ++i){
    const int row = m0 + wr*64 + i*16 + lg*4;
#pragma unroll
    for (int j = 0; j < 4; ++j){
      const int col = n0 + wc*64 + j*16 + lr;
#pragma unroll
      for (int r = 0; r < 4; ++r)
        Sb[((size_t)(row + r) << 10) + col] = f2bf(acc[i][j][r]);
    }
  }
}

// ---------------- K4b: row softmax over s (in place, zero-fill s>t) ----------------
__global__ __launch_bounds__(256) void k_softmax(u16* __restrict__ SW)
{
  const int bid = blockIdx.x;
  const int b = bid >> 10, t = bid & 1023;
  u16* row = SW + ((size_t)b << 20) + ((size_t)t << 10);
  const int i0 = threadIdx.x * 4;
  u16x4 v = *(const u16x4*)(row + i0);
  float x[4];
#pragma unroll
  for (int j = 0; j < 4; ++j) x[j] = (i0 + j <= t) ? bf2f(v[j]) : -1e30f;
  float m = fmaxf(fmaxf(x[0], x[1]), fmaxf(x[2], x[3]));
#pragma unroll
  for (int o = 1; o < 64; o <<= 1) m = fmaxf(m, __shfl_xor(m, o));
  __shared__ float redm[4], reds[4];
  if ((threadIdx.x & 63) == 0) redm[threadIdx.x >> 6] = m;
  __syncthreads();
  m = fmaxf(fmaxf(redm[0], redm[1]), fmaxf(redm[2], redm[3]));
  float e[4]; float s = 0.f;
#pragma unroll
  for (int j = 0; j < 4; ++j){ e[j] = __expf(x[j] - m); s += e[j]; }
#pragma unroll
  for (int o = 1; o < 64; o <<= 1) s += __shfl_xor(s, o);
  if ((threadIdx.x & 63) == 0) reds[threadIdx.x >> 6] = s;
  __syncthreads();
  s = reds[0] + reds[1] + reds[2] + reds[3];
  const float inv = 1.f / s;
  u16x4 o4;
#pragma unroll
  for (int j = 0; j < 4; ++j) o4[j] = f2bf(e[j] * inv);
  *(u16x4*)(row + i0) = o4;
}

// ---------------- K4c: Ctx[b,t,e] = sum_s W[b,t,s] * H[b,s,e] ----------------
__global__ __launch_bounds__(256) void k_pv(const u16* __restrict__ SW,
    const u16* __restrict__ Harc, u16* __restrict__ Ctx)
{
  __shared__ u16 As[128][40];   // W rows t, cols s
  __shared__ u16 Bs[128][40];   // H^T rows e, cols s
  const int tid = threadIdx.x;
  const int bz = blockIdx.z;
  const int t0 = blockIdx.x * 128;
  const int e0 = blockIdx.y * 128;
  const u16* Wb = SW + ((size_t)bz << 20);
  const u16* Hb = Harc + (size_t)bz * NS * HD;
  u16* Cb = Ctx + (size_t)bz * NS * HD;
  const int l = tid & 63, w = tid >> 6;
  const int wr = w >> 1, wc = w & 1;
  const int lr = l & 15, lg = l >> 4;
  const int srow = tid >> 1, shalf = (tid & 1) * 16;
  const int sIdx = tid & 31, ec = tid >> 5;
  const int ksteps = (blockIdx.x + 1) * 4;    // s < t0 + 128 (causal bound)
  f32x4 acc[4][4] = {};
  for (int ks = 0; ks < ksteps; ++ks){
    const int k0 = ks * 32;
    {
      const u16* a = Wb + ((size_t)(t0 + srow) << 10) + k0 + shalf;
      ushort8 a0 = *(const ushort8*)a, a1 = *(const ushort8*)(a+8);
      const u16* b = Hb + (size_t)(k0 + sIdx)*HD + e0 + ec*16;
      ushort8 b0 = *(const ushort8*)b, b1 = *(const ushort8*)(b+8);
      *(ushort8*)&As[srow][shalf] = a0; *(ushort8*)&As[srow][shalf+8] = a1;
#pragma unroll
      for (int i = 0; i < 8; ++i){
        Bs[ec*16 + i][sIdx] = b0[i];
        Bs[ec*16 + 8 + i][sIdx] = b1[i];
      }
    }
    __syncthreads();
    bf16x8 af[4], bfr[4];
#pragma unroll
    for (int i = 0; i < 4; ++i){
      af[i]  = *(const bf16x8*)&As[wr*64 + i*16 + lr][lg*8];
      bfr[i] = *(const bf16x8*)&Bs[wc*64 + i*16 + lr][lg*8];
    }
#pragma unroll
    for (int i = 0; i < 4; ++i)
#pragma unroll
      for (int j = 0; j < 4; ++j)
        acc[i][j] = MFMA16(af[i], bfr[j], acc[i][j]);
    __syncthreads();
  }
#pragma unroll
  for (int i = 0; i < 4; ++i){
    const int row = t0 + wr*64 + i*16 + lg*4;
#pragma unroll
    for (int j = 0; j < 4; ++j){
      const int col = e0 + wc*64 + j*16 + lr;
#pragma unroll
      for (int r = 0; r < 4; ++r)
        Cb[(size_t)(row + r)*HD + col] = f2bf(acc[i][j][r]);
    }
  }
}

// ---------------- K5: out = [H|ctx] @ fc^T + b  (MFMA, N=128) ----------------
__global__ __launch_bounds__(256) void k_out2(const u16* __restrict__ Harc,
    const u16* __restrict__ Ctx, const u16* __restrict__ fc_bf,
    const float* __restrict__ fcb, float* __restrict__ out)
{
  __shared__ u16 As[128][40];
  __shared__ u16 Bs[128][40];
  const int tid = threadIdx.x;
  const int m0 = blockIdx.x * 128;
  const int l = tid & 63, w = tid >> 6;
  const int wr = w >> 1, wc = w & 1;
  const int lr = l & 15, lg = l >> 4;
  const int srow = tid >> 1, shalf = (tid & 1) * 16;
  f32x4 acc[4][4] = {};
  for (int k0 = 0; k0 < 2048; k0 += 32){
    {
      const u16* abase = (k0 < 1024) ? Harc : Ctx;
      const u16* a = abase + (size_t)(m0 + srow)*HD + (k0 & 1023) + shalf;
      ushort8 a0 = *(const ushort8*)a, a1 = *(const ushort8*)(a+8);
      const u16* b = fc_bf + (size_t)srow*2048 + k0 + shalf;
      ushort8 b0 = *(const ushort8*)b, b1 = *(const ushort8*)(b+8);
      *(ushort8*)&As[srow][shalf] = a0; *(ushort8*)&As[srow][shalf+8] = a1;
      *(ushort8*)&Bs[srow][shalf] = b0; *(ushort8*)&Bs[srow][shalf+8] = b1;
    }
    __syncthreads();
    bf16x8 af[4], bfr[4];
#pragma unroll
    for (int i = 0; i < 4; ++i){
      af[i]  = *(const bf16x8*)&As[wr*64 + i*16 + lr][lg*8];
      bfr[i] = *(const bf16x8*)&Bs[wc*64 + i*16 + lr][lg*8];
    }
#pragma unroll
    for (int i = 0; i < 4; ++i)
#pragma unroll
      for (int j = 0; j < 4; ++j)
        acc[i][j] = MFMA16(af[i], bfr[j], acc[i][j]);
    __syncthreads();
  }
#pragma unroll
  for (int i = 0; i < 4; ++i){
    const int row = m0 + wr*64 + i*16 + lg*4;
#pragma unroll
    for (int j = 0; j < 4; ++j){
      const int col = wc*64 + j*16 + lr;
      const float bias = fcb[col];
#pragma unroll
      for (int r = 0; r < 4; ++r)
        out[(size_t)(row + r)*NV + col] = acc[i][j][r] + bias;
    }
  }
}

extern "C" void kernel_launch(void* const* d_in, const int* in_sizes, int n_in,
                              void* d_out, int out_size, void* d_ws, size_t ws_size,
                              hipStream_t stream)
{
  const int*   x   = (const int*)  d_in[0];
  const float* emb = (const float*)d_in[1];
  const float* wxw = (const float*)d_in[2];
  const float* wxb = (const float*)d_in[3];
  const float* whw = (const float*)d_in[4];
  const float* whb = (const float*)d_in[5];
  const float* waw = (const float*)d_in[6];
  const float* wab = (const float*)d_in[7];
  const float* fcw = (const float*)d_in[8];
  const float* fcb = (const float*)d_in[9];
  float* out = (float*)d_out;

  char* ws = (char*)d_ws;
  unsigned int* cnt = (unsigned int*)(ws);            // 4 KB
  float* hstate = (float*)(ws + 4096);                // 256 KB
  float* XW     = (float*)(ws + 266240);              // 512 KB
  u16*   Harc   = (u16*)  (ws + 790528);              // 64 MB  H archive (bf16)
  u16*   Aarc   = (u16*)  (ws + 67899392);            // 64 MB  A archive; later reused as Ctx
  u16*   SW     = (u16*)  (ws + 135008256);           // 64 MB  scores/weights (in place)
  u16*   wa_bf  = (u16*)  (ws + 135008256);           // aliases SW (dead before scores)
  u16*   fc_bf  = (u16*)  (ws + 202117120);           // 512 KB  -> total ~202.6 MB
  u16*   Ctx    = Aarc;                               // PV output overwrites A archive

  (void)hipMemsetAsync(ws, 0, 266240, stream);        // cnt + hstate zeros

  k_cvt<<<dim3(5120), dim3(256), 0, stream>>>(waw, fcw, wa_bf, fc_bf);
  k_xw<<<dim3(NV), dim3(256), 0, stream>>>(emb, wxw, wxb, XW);

  {
    void* args[] = { (void*)&x, (void*)&whw, (void*)&whb, (void*)&XW,
                     (void*)&hstate, (void*)&Harc, (void*)&cnt };
    (void)hipLaunchCooperativeKernel((const void*)k_scan2, dim3(256), dim3(256),
                                     args, 0, stream);
  }

  k_gemm_A<<<dim3(256, 8), dim3(256), 0, stream>>>(Harc, wa_bf, wab, Aarc);
  k_scores<<<dim3(8, 8, 32), dim3(256), 0, stream>>>(Harc, Aarc, SW);
  k_softmax<<<dim3(32768), dim3(256), 0, stream>>>(SW);
  k_pv<<<dim3(8, 8, 32), dim3(256), 0, stream>>>(SW, Harc, Ctx);
  k_out2<<<dim3(256), dim3(256), 0, stream>>>(Harc, Ctx, fc_bf, fcb, out);
}

// Round 8
// 6551.079 us; speedup vs baseline: 5.9040x; 1.0000x over previous
//
#include <hip/hip_runtime.h>
#include <hip/hip_bf16.h>
#include <hip/hip_cooperative_groups.h>

#define NV 128
#define NE 256
#define HD 1024
#define NB 32
#define NS 1024

typedef unsigned short u16;
typedef unsigned short ushort8 __attribute__((ext_vector_type(8)));
typedef unsigned short u16x4 __attribute__((ext_vector_type(4)));
typedef short bf16x8 __attribute__((ext_vector_type(8)));
typedef float f32x4 __attribute__((ext_vector_type(4)));

#define MFMA16(a, b, c) __builtin_amdgcn_mfma_f32_16x16x32_bf16(a, b, c, 0, 0, 0)

__device__ __forceinline__ float bf2f(u16 u){
  unsigned int x = ((unsigned int)u) << 16;
  return __builtin_bit_cast(float, x);
}
__device__ __forceinline__ u16 f2bf(float f){
  unsigned int u = __builtin_bit_cast(unsigned int, f);
  unsigned int r = u + 0x7fffu + ((u >> 16) & 1u);
  return (u16)(r >> 16);
}

// ---------------- K0: fp32 weights -> bf16 copies ----------------
__global__ __launch_bounds__(256) void k_cvt(const float* __restrict__ waw,
    const float* __restrict__ fcw, u16* __restrict__ wa_bf, u16* __restrict__ fc_bf)
{
  const int i = blockIdx.x * 256 + threadIdx.x;
  if (i < 1048576) wa_bf[i] = f2bf(waw[i]);
  const int j = i - 1048576;
  if (j >= 0 && j < 262144) fc_bf[j] = f2bf(fcw[j]);
}

// ---------------- K1: XW[v,h] = sum_e emb[v,e]*Wx[h,e] + Wx_b[h] ----------------
__global__ __launch_bounds__(256) void k_xw(const float* __restrict__ emb,
    const float* __restrict__ wxw, const float* __restrict__ wxb,
    float* __restrict__ XW)
{
  __shared__ float es[NE];
  const int v = blockIdx.x;
  for (int i = threadIdx.x; i < NE; i += 256) es[i] = emb[v*NE + i];
  __syncthreads();
  for (int h = threadIdx.x; h < HD; h += 256){
    const float* wr = wxw + (size_t)h * NE;
    float acc = 0.f;
#pragma unroll 4
    for (int e = 0; e < NE; e += 4){
      float4 w4 = *reinterpret_cast<const float4*>(wr + e);
      acc += w4.x*es[e] + w4.y*es[e+1] + w4.z*es[e+2] + w4.w*es[e+3];
    }
    XW[(size_t)v*HD + h] = acc + wxb[h];
  }
}

// ---------------- K2: RNN scan ----------------
// R5 structure + barrier VERBATIM (proven); only the per-thread work tiling
// changed: R=4 rows x K=32 k-slice (kc = tid&31, rg = tid>>5), cutting LDS
// reads 4x (MAC:LDS = 4:1). Reduction: 5-level shfl_xor within the 32-lane
// kc-half, then a local equality-chain select (all lanes hold all 16 sums).
__global__ __launch_bounds__(256, 2) void k_scan2(const int* __restrict__ x,
    const float* __restrict__ whw, const float* __restrict__ whb,
    const float* __restrict__ XW, float* __restrict__ hstate,
    u16* __restrict__ Harc, unsigned int* __restrict__ cnt)
{
  __shared__ __align__(16) float hs[4096];   // 4 batches x 1024
  __shared__ int xs[4096];                   // 4 batches x 1024 token ids
  const int tid = threadIdx.x;
  const int g = blockIdx.x & 7;
  const int m = blockIdx.x >> 3;
  const int kc = tid & 31;
  const int rg = tid >> 5;
  const int row0 = m*32 + rg*4;

  for (int i = tid; i < 4096; i += 256) xs[i] = x[g*4096 + i];

  // Wh fragments: 4 rows x 32 k (8 float4), k-rotated to spread LDS banks
  float4 wv[4][8];
#pragma unroll
  for (int r = 0; r < 4; ++r)
#pragma unroll
    for (int j = 0; j < 8; ++j)
      wv[r][j] = *reinterpret_cast<const float4*>(
          whw + (size_t)(row0 + r)*HD + kc*32 + ((4*(j + kc)) & 31));

  // lane kc<16 of each rg writes (row rr, batch bb)
  const int rr = row0 + (kc & 3);
  const int bb = kc >> 2;
  const float bias = whb[rr];
  unsigned int* bar = cnt + g*32;            // 128B-padded per-group counter
  __syncthreads();                           // xs ready

  for (int t = 0; t < NS; ++t){
    const float* hin  = hstate + (size_t)(t & 1)*(NB*HD) + g*4*HD;
    float*       hout = hstate + (size_t)((t & 1)^1)*(NB*HD) + g*4*HD;
    // stage 4 batch rows of h (16 KB), coalesced (buffer 0 pre-zeroed for t=0)
#pragma unroll
    for (int q = 0; q < 4; ++q)
      *reinterpret_cast<float4*>(&hs[q*1024 + tid*4]) =
        *reinterpret_cast<const float4*>(hin + q*1024 + tid*4);
    // prefetch per-step gather operand (hide IC latency under FMAs)
    float xwv = 0.f;
    if (kc < 16){
      const int xv = xs[bb*1024 + t];
      xwv = XW[(size_t)xv*HD + rr];
    }
    __syncthreads();

    float acc[4][4] = {};   // [row r][batch b]
#pragma unroll
    for (int j = 0; j < 8; ++j){
      const int off = kc*32 + ((4*(j + kc)) & 31);
      float4 h4[4];
#pragma unroll
      for (int b = 0; b < 4; ++b)
        h4[b] = *reinterpret_cast<const float4*>(&hs[b*1024 + off]);
#pragma unroll
      for (int r = 0; r < 4; ++r)
#pragma unroll
        for (int b = 0; b < 4; ++b)
          acc[r][b] += wv[r][j].x*h4[b].x + wv[r][j].y*h4[b].y
                     + wv[r][j].z*h4[b].z + wv[r][j].w*h4[b].w;
    }
    // butterfly reduce across the 32 kc-lanes (stays within each 32-lane half)
#pragma unroll
    for (int mm = 1; mm <= 16; mm <<= 1)
#pragma unroll
      for (int r = 0; r < 4; ++r)
#pragma unroll
        for (int b = 0; b < 4; ++b)
          acc[r][b] += __shfl_xor(acc[r][b], mm);
    // all lanes now hold all 16 totals; lane kc<16 takes acc[kc&3][kc>>2]
    float sv = acc[0][0];
#pragma unroll
    for (int r = 0; r < 4; ++r)
#pragma unroll
      for (int b = 0; b < 4; ++b)
        if ((kc & 15) == b*4 + r) sv = acc[r][b];

    if (kc < 16){
      const float val = tanhf(xwv + bias + sv);
      // write-through store: IC-visible after vmcnt drain, no dirty L2 line
      __hip_atomic_store(&hout[bb*HD + rr], val, __ATOMIC_RELAXED,
                         __HIP_MEMORY_SCOPE_AGENT);
      Harc[(((size_t)(g*4 + bb))*NS + t)*HD + rr] = f2bf(val);
    }
    __syncthreads();   // per-wave vmcnt(0) before s_barrier: stores visible
    if (tid == 0){
      __hip_atomic_fetch_add(bar, 1u, __ATOMIC_RELAXED, __HIP_MEMORY_SCOPE_AGENT);
      const unsigned int target = 32u*(unsigned)(t+1);
      while (__hip_atomic_load(bar, __ATOMIC_RELAXED, __HIP_MEMORY_SCOPE_AGENT) < target)
        __builtin_amdgcn_s_sleep(1);
      __builtin_amdgcn_fence(__ATOMIC_ACQUIRE, "agent");  // one L1/L2 inv per step
    }
    __syncthreads();
  }
}

// ---------------- K3: A = H @ Wa^T + b  (MFMA, 128x128 tile) ----------------
__global__ __launch_bounds__(256) void k_gemm_A(const u16* __restrict__ Harc,
    const u16* __restrict__ wa_bf, const float* __restrict__ wab,
    u16* __restrict__ Aarc)
{
  __shared__ u16 As[128][40];
  __shared__ u16 Bs[128][40];
  const int tid = threadIdx.x;
  const int m0 = blockIdx.x * 128;
  const int n0 = blockIdx.y * 128;
  const int l = tid & 63, w = tid >> 6;
  const int wr = w >> 1, wc = w & 1;
  const int lr = l & 15, lg = l >> 4;
  const int srow = tid >> 1, shalf = (tid & 1) * 16;
  f32x4 acc[4][4] = {};
  for (int k0 = 0; k0 < 1024; k0 += 32){
    {
      const u16* a = Harc + (size_t)(m0 + srow)*HD + k0 + shalf;
      ushort8 a0 = *(const ushort8*)a, a1 = *(const ushort8*)(a+8);
      const u16* b = wa_bf + (size_t)(n0 + srow)*HD + k0 + shalf;
      ushort8 b0 = *(const ushort8*)b, b1 = *(const ushort8*)(b+8);
      *(ushort8*)&As[srow][shalf] = a0; *(ushort8*)&As[srow][shalf+8] = a1;
      *(ushort8*)&Bs[srow][shalf] = b0; *(ushort8*)&Bs[srow][shalf+8] = b1;
    }
    __syncthreads();
    bf16x8 af[4], bfr[4];
#pragma unroll
    for (int i = 0; i < 4; ++i){
      af[i]  = *(const bf16x8*)&As[wr*64 + i*16 + lr][lg*8];
      bfr[i] = *(const bf16x8*)&Bs[wc*64 + i*16 + lr][lg*8];
    }
#pragma unroll
    for (int i = 0; i < 4; ++i)
#pragma unroll
      for (int j = 0; j < 4; ++j)
        acc[i][j] = MFMA16(af[i], bfr[j], acc[i][j]);
    __syncthreads();
  }
#pragma unroll
  for (int i = 0; i < 4; ++i){
    const int row = m0 + wr*64 + i*16 + lg*4;
#pragma unroll
    for (int j = 0; j < 4; ++j){
      const int col = n0 + wc*64 + j*16 + lr;
      const float bias = wab[col];
#pragma unroll
      for (int r = 0; r < 4; ++r)
        Aarc[(size_t)(row + r)*HD + col] = f2bf(acc[i][j][r] + bias);
    }
  }
}

// ---------------- K4a: S[b,t,s] = H[b,t]·A[b,s]  (causal tiles only) ----------------
__global__ __launch_bounds__(256) void k_scores(const u16* __restrict__ Harc,
    const u16* __restrict__ Aarc, u16* __restrict__ SW)
{
  if (blockIdx.x > blockIdx.y) return;   // s-tile beyond t-tile: never read
  __shared__ u16 As[128][40];
  __shared__ u16 Bs[128][40];
  const int tid = threadIdx.x;
  const int bz = blockIdx.z;
  const int m0 = blockIdx.y * 128;   // t
  const int n0 = blockIdx.x * 128;   // s
  const u16* Hb = Harc + (size_t)bz * NS * HD;
  const u16* Ab = Aarc + (size_t)bz * NS * HD;
  u16* Sb = SW + ((size_t)bz << 20);
  const int l = tid & 63, w = tid >> 6;
  const int wr = w >> 1, wc = w & 1;
  const int lr = l & 15, lg = l >> 4;
  const int srow = tid >> 1, shalf = (tid & 1) * 16;
  f32x4 acc[4][4] = {};
  for (int k0 = 0; k0 < 1024; k0 += 32){
    {
      const u16* a = Hb + (size_t)(m0 + srow)*HD + k0 + shalf;
      ushort8 a0 = *(const ushort8*)a, a1 = *(const ushort8*)(a+8);
      const u16* b = Ab + (size_t)(n0 + srow)*HD + k0 + shalf;
      ushort8 b0 = *(const ushort8*)b, b1 = *(const ushort8*)(b+8);
      *(ushort8*)&As[srow][shalf] = a0; *(ushort8*)&As[srow][shalf+8] = a1;
      *(ushort8*)&Bs[srow][shalf] = b0; *(ushort8*)&Bs[srow][shalf+8] = b1;
    }
    __syncthreads();
    bf16x8 af[4], bfr[4];
#pragma unroll
    for (int i = 0; i < 4; ++i){
      af[i]  = *(const bf16x8*)&As[wr*64 + i*16 + lr][lg*8];
      bfr[i] = *(const bf16x8*)&Bs[wc*64 + i*16 + lr][lg*8];
    }
#pragma unroll
    for (int i = 0; i < 4; ++i)
#pragma unroll
      for (int j = 0; j < 4; ++j)
        acc[i][j] = MFMA16(af[i], bfr[j], acc[i][j]);
    __syncthreads();
  }
#pragma unroll
  for (int i = 0; i < 4; ++i){
    const int row = m0 + wr*64 + i*16 + lg*4;
#pragma unroll
    for (int j = 0; j < 4; ++j){
      const int col = n0 + wc*64 + j*16 + lr;
#pragma unroll
      for (int r = 0; r < 4; ++r)
        Sb[((size_t)(row + r) << 10) + col] = f2bf(acc[i][j][r]);
    }
  }
}

// ---------------- K4b: row softmax over s (in place, zero-fill s>t) ----------------
__global__ __launch_bounds__(256) void k_softmax(u16* __restrict__ SW)
{
  const int bid = blockIdx.x;
  const int b = bid >> 10, t = bid & 1023;
  u16* row = SW + ((size_t)b << 20) + ((size_t)t << 10);
  const int i0 = threadIdx.x * 4;
  u16x4 v = *(const u16x4*)(row + i0);
  float x[4];
#pragma unroll
  for (int j = 0; j < 4; ++j) x[j] = (i0 + j <= t) ? bf2f(v[j]) : -1e30f;
  float m = fmaxf(fmaxf(x[0], x[1]), fmaxf(x[2], x[3]));
#pragma unroll
  for (int o = 1; o < 64; o <<= 1) m = fmaxf(m, __shfl_xor(m, o));
  __shared__ float redm[4], reds[4];
  if ((threadIdx.x & 63) == 0) redm[threadIdx.x >> 6] = m;
  __syncthreads();
  m = fmaxf(fmaxf(redm[0], redm[1]), fmaxf(redm[2], redm[3]));
  float e[4]; float s = 0.f;
#pragma unroll
  for (int j = 0; j < 4; ++j){ e[j] = __expf(x[j] - m); s += e[j]; }
#pragma unroll
  for (int o = 1; o < 64; o <<= 1) s += __shfl_xor(s, o);
  if ((threadIdx.x & 63) == 0) reds[threadIdx.x >> 6] = s;
  __syncthreads();
  s = reds[0] + reds[1] + reds[2] + reds[3];
  const float inv = 1.f / s;
  u16x4 o4;
#pragma unroll
  for (int j = 0; j < 4; ++j) o4[j] = f2bf(e[j] * inv);
  *(u16x4*)(row + i0) = o4;
}

// ---------------- K4c: Ctx[b,t,e] = sum_s W[b,t,s] * H[b,s,e] ----------------
__global__ __launch_bounds__(256) void k_pv(const u16* __restrict__ SW,
    const u16* __restrict__ Harc, u16* __restrict__ Ctx)
{
  __shared__ u16 As[128][40];   // W rows t, cols s
  __shared__ u16 Bs[128][40];   // H^T rows e, cols s
  const int tid = threadIdx.x;
  const int bz = blockIdx.z;
  const int t0 = blockIdx.x * 128;
  const int e0 = blockIdx.y * 128;
  const u16* Wb = SW + ((size_t)bz << 20);
  const u16* Hb = Harc + (size_t)bz * NS * HD;
  u16* Cb = Ctx + (size_t)bz * NS * HD;
  const int l = tid & 63, w = tid >> 6;
  const int wr = w >> 1, wc = w & 1;
  const int lr = l & 15, lg = l >> 4;
  const int srow = tid >> 1, shalf = (tid & 1) * 16;
  const int sIdx = tid & 31, ec = tid >> 5;
  const int ksteps = (blockIdx.x + 1) * 4;    // s < t0 + 128 (causal bound)
  f32x4 acc[4][4] = {};
  for (int ks = 0; ks < ksteps; ++ks){
    const int k0 = ks * 32;
    {
      const u16* a = Wb + ((size_t)(t0 + srow) << 10) + k0 + shalf;
      ushort8 a0 = *(const ushort8*)a, a1 = *(const ushort8*)(a+8);
      const u16* b = Hb + (size_t)(k0 + sIdx)*HD + e0 + ec*16;
      ushort8 b0 = *(const ushort8*)b, b1 = *(const ushort8*)(b+8);
      *(ushort8*)&As[srow][shalf] = a0; *(ushort8*)&As[srow][shalf+8] = a1;
#pragma unroll
      for (int i = 0; i < 8; ++i){
        Bs[ec*16 + i][sIdx] = b0[i];
        Bs[ec*16 + 8 + i][sIdx] = b1[i];
      }
    }
    __syncthreads();
    bf16x8 af[4], bfr[4];
#pragma unroll
    for (int i = 0; i < 4; ++i){
      af[i]  = *(const bf16x8*)&As[wr*64 + i*16 + lr][lg*8];
      bfr[i] = *(const bf16x8*)&Bs[wc*64 + i*16 + lr][lg*8];
    }
#pragma unroll
    for (int i = 0; i < 4; ++i)
#pragma unroll
      for (int j = 0; j < 4; ++j)
        acc[i][j] = MFMA16(af[i], bfr[j], acc[i][j]);
    __syncthreads();
  }
#pragma unroll
  for (int i = 0; i < 4; ++i){
    const int row = t0 + wr*64 + i*16 + lg*4;
#pragma unroll
    for (int j = 0; j < 4; ++j){
      const int col = e0 + wc*64 + j*16 + lr;
#pragma unroll
      for (int r = 0; r < 4; ++r)
        Cb[(size_t)(row + r)*HD + col] = f2bf(acc[i][j][r]);
    }
  }
}

// ---------------- K5: out = [H|ctx] @ fc^T + b  (MFMA, N=128) ----------------
__global__ __launch_bounds__(256) void k_out2(const u16* __restrict__ Harc,
    const u16* __restrict__ Ctx, const u16* __restrict__ fc_bf,
    const float* __restrict__ fcb, float* __restrict__ out)
{
  __shared__ u16 As[128][40];
  __shared__ u16 Bs[128][40];
  const int tid = threadIdx.x;
  const int m0 = blockIdx.x * 128;
  const int l = tid & 63, w = tid >> 6;
  const int wr = w >> 1, wc = w & 1;
  const int lr = l & 15, lg = l >> 4;
  const int srow = tid >> 1, shalf = (tid & 1) * 16;
  f32x4 acc[4][4] = {};
  for (int k0 = 0; k0 < 2048; k0 += 32){
    {
      const u16* abase = (k0 < 1024) ? Harc : Ctx;
      const u16* a = abase + (size_t)(m0 + srow)*HD + (k0 & 1023) + shalf;
      ushort8 a0 = *(const ushort8*)a, a1 = *(const ushort8*)(a+8);
      const u16* b = fc_bf + (size_t)srow*2048 + k0 + shalf;
      ushort8 b0 = *(const ushort8*)b, b1 = *(const ushort8*)(b+8);
      *(ushort8*)&As[srow][shalf] = a0; *(ushort8*)&As[srow][shalf+8] = a1;
      *(ushort8*)&Bs[srow][shalf] = b0; *(ushort8*)&Bs[srow][shalf+8] = b1;
    }
    __syncthreads();
    bf16x8 af[4], bfr[4];
#pragma unroll
    for (int i = 0; i < 4; ++i){
      af[i]  = *(const bf16x8*)&As[wr*64 + i*16 + lr][lg*8];
      bfr[i] = *(const bf16x8*)&Bs[wc*64 + i*16 + lr][lg*8];
    }
#pragma unroll
    for (int i = 0; i < 4; ++i)
#pragma unroll
      for (int j = 0; j < 4; ++j)
        acc[i][j] = MFMA16(af[i], bfr[j], acc[i][j]);
    __syncthreads();
  }
#pragma unroll
  for (int i = 0; i < 4; ++i){
    const int row = m0 + wr*64 + i*16 + lg*4;
#pragma unroll
    for (int j = 0; j < 4; ++j){
      const int col = wc*64 + j*16 + lr;
      const float bias = fcb[col];
#pragma unroll
      for (int r = 0; r < 4; ++r)
        out[(size_t)(row + r)*NV + col] = acc[i][j][r] + bias;
    }
  }
}

extern "C" void kernel_launch(void* const* d_in, const int* in_sizes, int n_in,
                              void* d_out, int out_size, void* d_ws, size_t ws_size,
                              hipStream_t stream)
{
  const int*   x   = (const int*)  d_in[0];
  const float* emb = (const float*)d_in[1];
  const float* wxw = (const float*)d_in[2];
  const float* wxb = (const float*)d_in[3];
  const float* whw = (const float*)d_in[4];
  const float* whb = (const float*)d_in[5];
  const float* waw = (const float*)d_in[6];
  const float* wab = (const float*)d_in[7];
  const float* fcw = (const float*)d_in[8];
  const float* fcb = (const float*)d_in[9];
  float* out = (float*)d_out;

  char* ws = (char*)d_ws;
  unsigned int* cnt = (unsigned int*)(ws);            // 4 KB
  float* hstate = (float*)(ws + 4096);                // 256 KB
  float* XW     = (float*)(ws + 266240);              // 512 KB
  u16*   Harc   = (u16*)  (ws + 790528);              // 64 MB  H archive (bf16)
  u16*   Aarc   = (u16*)  (ws + 67899392);            // 64 MB  A archive; later reused as Ctx
  u16*   SW     = (u16*)  (ws + 135008256);           // 64 MB  scores/weights (in place)
  u16*   wa_bf  = (u16*)  (ws + 135008256);           // aliases SW (dead before scores)
  u16*   fc_bf  = (u16*)  (ws + 202117120);           // 512 KB  -> total ~202.6 MB
  u16*   Ctx    = Aarc;                               // PV output overwrites A archive

  (void)hipMemsetAsync(ws, 0, 266240, stream);        // cnt + hstate zeros

  k_cvt<<<dim3(5120), dim3(256), 0, stream>>>(waw, fcw, wa_bf, fc_bf);
  k_xw<<<dim3(NV), dim3(256), 0, stream>>>(emb, wxw, wxb, XW);

  {
    void* args[] = { (void*)&x, (void*)&whw, (void*)&whb, (void*)&XW,
                     (void*)&hstate, (void*)&Harc, (void*)&cnt };
    (void)hipLaunchCooperativeKernel((const void*)k_scan2, dim3(256), dim3(256),
                                     args, 0, stream);
  }

  k_gemm_A<<<dim3(256, 8), dim3(256), 0, stream>>>(Harc, wa_bf, wab, Aarc);
  k_scores<<<dim3(8, 8, 32), dim3(256), 0, stream>>>(Harc, Aarc, SW);
  k_softmax<<<dim3(32768), dim3(256), 0, stream>>>(SW);
  k_pv<<<dim3(8, 8, 32), dim3(256), 0, stream>>>(SW, Harc, Ctx);
  k_out2<<<dim3(256), dim3(256), 0, stream>>>(Harc, Ctx, fc_bf, fcb, out);
}